// Round 1
// baseline (517.614 us; speedup 1.0000x reference)
//
#include <hip/hip_runtime.h>

#define NSP 32768   // 32*32*32 spatial positions
#define EPS 1e-5f

// ---------------------------------------------------------------------------
// General channel-major GEMM: Out[o*N + n] = act(bias[o] + sum_k W[o*sO+k*sC]*X[k*N+n] (+resid))
// Tiles: 64 o x 64 n x 32 k. 256 threads, 4x4 micro-tile per thread.
// ---------------------------------------------------------------------------
__global__ __launch_bounds__(256) void gemm_cn(
    const float* __restrict__ W, int sO, int sC,
    const float* __restrict__ X, const float* __restrict__ bias,
    const float* __restrict__ resid, float* __restrict__ Out,
    int K, int N, int do_relu)
{
    __shared__ float Ws[32][65];
    __shared__ float Xs[32][65];
    const int tid = threadIdx.x;
    const int tx = tid & 15, ty = tid >> 4;
    const int o0 = blockIdx.y * 64;
    const int n0 = blockIdx.x * 64;
    float acc[4][4] = {};

    for (int k0 = 0; k0 < K; k0 += 32) {
        for (int i = tid; i < 2048; i += 256) {
            int o = i & 63, kk = i >> 6;
            Ws[kk][o] = W[(o0 + o) * sO + (k0 + kk) * sC];
        }
        for (int i = tid; i < 2048; i += 256) {
            int n = i & 63, kk = i >> 6;
            Xs[kk][n] = X[(k0 + kk) * N + n0 + n];
        }
        __syncthreads();
        for (int kk = 0; kk < 32; ++kk) {
            float xr[4], wr[4];
            #pragma unroll
            for (int j = 0; j < 4; ++j) xr[j] = Xs[kk][tx + 16 * j];
            #pragma unroll
            for (int i = 0; i < 4; ++i) wr[i] = Ws[kk][ty + 16 * i];
            #pragma unroll
            for (int i = 0; i < 4; ++i)
                #pragma unroll
                for (int j = 0; j < 4; ++j)
                    acc[i][j] += wr[i] * xr[j];
        }
        __syncthreads();
    }

    #pragma unroll
    for (int i = 0; i < 4; ++i) {
        int o = o0 + ty + 16 * i;
        float b = bias ? bias[o] : 0.f;
        #pragma unroll
        for (int j = 0; j < 4; ++j) {
            int n = n0 + tx + 16 * j;
            float v = acc[i][j] + b;
            if (resid) v += resid[o * N + n];
            if (do_relu) v = fmaxf(v, 0.f);
            Out[o * N + n] = v;
        }
    }
}

// ---------------------------------------------------------------------------
// Neighborhood attention: one thread per (group, position).
// qkv layout: [384][NSP], q = rows 0..127, k = 128..255, v = 256..383 (c = g*16+d)
// ---------------------------------------------------------------------------
__global__ __launch_bounds__(256) void attn_kernel(
    const float* __restrict__ qkv, const float* __restrict__ rpb,
    float* __restrict__ sam)
{
    const int g = blockIdx.y;
    const int n = blockIdx.x * 256 + threadIdx.x;
    const int h = n >> 10, w = (n >> 5) & 31, z = n & 31;
    const int ih0 = min(max(h - 1, 0), 29);
    const int iw0 = min(max(w - 1, 0), 29);
    const int iz0 = min(max(z - 1, 0), 29);

    const float* qp = qkv + (g * 16) * NSP + n;
    const float* kbase = qkv + (128 + g * 16) * NSP;
    const float* vbase = qkv + (256 + g * 16) * NSP;

    float q[16];
    #pragma unroll
    for (int d = 0; d < 16; ++d) q[d] = qp[d * NSP];

    float logits[27];
    int idx = 0;
    for (int kh = 0; kh < 3; ++kh)
    for (int kw = 0; kw < 3; ++kw)
    for (int kz = 0; kz < 3; ++kz) {
        int hh = ih0 + kh, ww = iw0 + kw, zz = iz0 + kz;
        int nb = (hh << 10) + (ww << 5) + zz;
        float s = 0.f;
        #pragma unroll
        for (int d = 0; d < 16; ++d) s += q[d] * kbase[d * NSP + nb];
        int rh = hh - h + 2, rw = ww - w + 2, rz = zz - z + 2;
        logits[idx++] = s * 0.25f + rpb[g * 125 + rh * 25 + rw * 5 + rz];
    }

    float mx = -1e30f;
    #pragma unroll
    for (int i = 0; i < 27; ++i) mx = fmaxf(mx, logits[i]);
    float sum = 0.f;
    #pragma unroll
    for (int i = 0; i < 27; ++i) { logits[i] = __expf(logits[i] - mx); sum += logits[i]; }
    float inv = 1.f / sum;

    float out[16] = {};
    idx = 0;
    for (int kh = 0; kh < 3; ++kh)
    for (int kw = 0; kw < 3; ++kw)
    for (int kz = 0; kz < 3; ++kz) {
        int nb = ((ih0 + kh) << 10) + ((iw0 + kw) << 5) + (iz0 + kz);
        float a = logits[idx++] * inv;
        #pragma unroll
        for (int d = 0; d < 16; ++d) out[d] += a * vbase[d * NSP + nb];
    }
    #pragma unroll
    for (int d = 0; d < 16; ++d) sam[(g * 16 + d) * NSP + n] = out[d];
}

// ---------------------------------------------------------------------------
// Instance norm over spatial dims, one block per channel. Optional +x (skip).
// ---------------------------------------------------------------------------
__global__ __launch_bounds__(256) void inorm_kernel(
    const float* __restrict__ in, const float* __restrict__ addx,
    float* __restrict__ out)
{
    const int c = blockIdx.x;
    const float* p = in + c * NSP;
    float s = 0.f, ss = 0.f;
    for (int i = threadIdx.x; i < NSP; i += 256) {
        float v = p[i];
        s += v; ss += v * v;
    }
    __shared__ float red[2][4];
    __shared__ float mb, ib;
    for (int off = 32; off > 0; off >>= 1) {
        s  += __shfl_down(s, off);
        ss += __shfl_down(ss, off);
    }
    int wid = threadIdx.x >> 6;
    if ((threadIdx.x & 63) == 0) { red[0][wid] = s; red[1][wid] = ss; }
    __syncthreads();
    if (threadIdx.x == 0) {
        float S  = red[0][0] + red[0][1] + red[0][2] + red[0][3];
        float SS = red[1][0] + red[1][1] + red[1][2] + red[1][3];
        float m = S / NSP;
        float var = SS / NSP - m * m;
        mb = m; ib = rsqrtf(var + EPS);
    }
    __syncthreads();
    float m = mb, inv = ib;
    if (addx) {
        const float* xp = addx + c * NSP;
        for (int i = threadIdx.x; i < NSP; i += 256)
            out[c * NSP + i] = (p[i] - m) * inv + xp[i];
    } else {
        for (int i = threadIdx.x; i < NSP; i += 256)
            out[c * NSP + i] = (p[i] - m) * inv;
    }
}

// ---------------------------------------------------------------------------
// 2x2x2 max pool: 128 * 16^3 outputs
// ---------------------------------------------------------------------------
__global__ __launch_bounds__(256) void pool_kernel(
    const float* __restrict__ skip, float* __restrict__ down)
{
    int m = blockIdx.x * 256 + threadIdx.x;   // < 524288
    int c = m >> 12;
    int r = m & 4095;
    int oh = r >> 8, ow = (r >> 4) & 15, oz = r & 15;
    const float* p = skip + c * NSP + (oh * 2) * 1024 + (ow * 2) * 32 + oz * 2;
    float mx = -1e30f;
    #pragma unroll
    for (int dh = 0; dh < 2; ++dh)
    #pragma unroll
    for (int dw = 0; dw < 2; ++dw)
    #pragma unroll
    for (int dz = 0; dz < 2; ++dz)
        mx = fmaxf(mx, p[dh * 1024 + dw * 32 + dz]);
    down[m] = mx;
}

// ---------------------------------------------------------------------------
extern "C" void kernel_launch(void* const* d_in, const int* in_sizes, int n_in,
                              void* d_out, int out_size, void* d_ws, size_t ws_size,
                              hipStream_t stream)
{
    const float* x      = (const float*)d_in[0];
    const float* qkv_w  = (const float*)d_in[1];
    const float* qkv_b  = (const float*)d_in[2];
    const float* proj_w = (const float*)d_in[3];
    const float* proj_b = (const float*)d_in[4];
    const float* rpb    = (const float*)d_in[5];
    const float* w1     = (const float*)d_in[6];
    const float* b1     = (const float*)d_in[7];
    const float* w2     = (const float*)d_in[8];
    const float* b2     = (const float*)d_in[9];

    float* out  = (float*)d_out;
    float* down = out;              // 128*16^3 = 524288
    float* skip = out + 524288;     // 128*32^3 = 4194304

    char* ws = (char*)d_ws;
    float* qkv    = (float*)(ws);                 // 384*NSP = 50.3 MB
    float* sam    = (float*)(ws + 50331648);      // 128*NSP = 16.8 MB
    float* y      = (float*)(ws + 67108864);      // 128*NSP
    float* xn1    = (float*)(ws + 83886080);      // 128*NSP
    float* hidden = (float*)(ws);                 // 512*NSP = 67.1 MB, overlays dead qkv+sam
    float* t2     = y;                            // overlays dead y

    const int N = NSP;

    // 1) qkv = x @ qkv_w^T + b       (O=384, K=128)
    gemm_cn<<<dim3(512, 6), 256, 0, stream>>>(qkv_w, 128, 1, x, qkv_b, nullptr, qkv, 128, N, 0);
    // 2) neighborhood attention -> sam
    attn_kernel<<<dim3(128, 8), 256, 0, stream>>>(qkv, rpb, sam);
    // 3) proj                        (O=128, K=128)
    gemm_cn<<<dim3(512, 2), 256, 0, stream>>>(proj_w, 128, 1, sam, proj_b, nullptr, y, 128, N, 0);
    // 4) instance norm 1
    inorm_kernel<<<128, 256, 0, stream>>>(y, nullptr, xn1);
    // 5a) hidden = relu(xn1 @ w1 + b1)   (O=512, K=128, W strides sO=1,sC=512)
    gemm_cn<<<dim3(512, 8), 256, 0, stream>>>(w1, 1, 512, xn1, b1, nullptr, hidden, 128, N, 1);
    // 5b) t2 = xn1 + hidden @ w2 + b2    (O=128, K=512, W strides sO=1,sC=128)
    gemm_cn<<<dim3(512, 2), 256, 0, stream>>>(w2, 1, 128, hidden, b2, xn1, t2, 512, N, 0);
    // 6) instance norm 2 + skip add -> skip (in d_out)
    inorm_kernel<<<128, 256, 0, stream>>>(t2, x, skip);
    // 7) maxpool -> down (in d_out)
    pool_kernel<<<2048, 256, 0, stream>>>(skip, down);
}

// Round 2
// 344.303 us; speedup vs baseline: 1.5034x; 1.5034x over previous
//
#include <hip/hip_runtime.h>

#define NSP 32768   // 32*32*32 spatial positions
#define EPS 1e-5f

typedef __attribute__((ext_vector_type(8))) __bf16 bf16x8;
typedef __attribute__((ext_vector_type(4))) float f32x4;
typedef __attribute__((ext_vector_type(8))) unsigned short us8;

union U8 { us8 u; bf16x8 b; };

__device__ __forceinline__ unsigned short f2bf(float f) {
    unsigned u = __float_as_uint(f);
    u += 0x7fff + ((u >> 16) & 1);
    return (unsigned short)(u >> 16);
}

// ---------------------------------------------------------------------------
// Weight prep: convert fp32 weights (arbitrary (sO,sC) strides) into bf16
// tiles laid out as the exact (XOR-swizzled) LDS image for 128x64 K-step
// tiles. Tile = 8192 shorts; within tile: byte = r*128 + c*16 ^ ((r&7)<<4) + 2j
// holds W[o = ob*128 + r][k = ks*64 + c*8 + j].
// ---------------------------------------------------------------------------
__global__ __launch_bounds__(256) void prep_w(
    const float* __restrict__ W, int sO, int sC, int ntk,
    unsigned short* __restrict__ Wsw, int total)
{
    int i = blockIdx.x * 256 + threadIdx.x;
    if (i >= total) return;
    int tile = i >> 13;
    int s = i & 8191;
    int r = s >> 6;
    int byte = (s & 63) << 1;
    int ub = byte ^ ((r & 7) << 4);
    int c = ub >> 4;
    int j = (ub >> 1) & 7;
    int ob = tile / ntk;
    int ks = tile - ob * ntk;
    int o = ob * 128 + r;
    int k = ks * 64 + c * 8 + j;
    Wsw[i] = f2bf(W[o * sO + k * sC]);
}

// ---------------------------------------------------------------------------
// bf16 MFMA GEMM: Out[o*N+n] = act(bias[o] + sum_k W[o][k] X[k][n] (+resid))
// Block tile 128(o) x 128(n) x BK=64. 4 waves (2x2), each 64x64 via 4x4
// mfma_f32_16x16x32_bf16 fragments. LDS XOR-swizzled (T2).
// ---------------------------------------------------------------------------
__global__ __launch_bounds__(256) void gemm_mfma(
    const unsigned short* __restrict__ Wsw,   // pre-swizzled bf16 tiles
    const void* __restrict__ X,               // [K][NSP], fp32 or bf16
    const float* __restrict__ bias,
    const float* __restrict__ resid,          // fp32 or null
    void* __restrict__ Out,                   // fp32 or bf16
    int K, int do_relu, int x_bf16, int out_bf16)
{
    __shared__ __align__(16) unsigned short Asm[8192];
    __shared__ __align__(16) unsigned short Bsm[8192];
    const int tid  = threadIdx.x;
    const int lane = tid & 63;
    const int wid  = tid >> 6;
    const int wr   = wid >> 1, wc = wid & 1;
    const int n0   = blockIdx.x << 7;
    const int o0   = blockIdx.y << 7;
    const int nk   = K >> 6;

    f32x4 acc[4][4];
    #pragma unroll
    for (int m = 0; m < 4; ++m)
        #pragma unroll
        for (int n = 0; n < 4; ++n)
            acc[m][n] = (f32x4){0.f, 0.f, 0.f, 0.f};

    const int r  = tid & 127;   // B-staging row (n within tile)
    const int kh = tid >> 7;    // 0/1: odd/even chunk set

    for (int ks = 0; ks < nk; ++ks) {
        // ---- A: linear copy of pre-swizzled global tile (coalesced, conflict-free)
        {
            const char* gbase = (const char*)(Wsw + (size_t)(blockIdx.y * nk + ks) * 8192);
            #pragma unroll
            for (int i = 0; i < 4; ++i) {
                us8 v = *(const us8*)(gbase + i * 4096 + tid * 16);
                *(us8*)((char*)Asm + i * 4096 + tid * 16) = v;
            }
        }
        // ---- B: fp32->bf16 (or bf16 direct) transpose-stage, rotated chunks
        #pragma unroll
        for (int i = 0; i < 4; ++i) {
            int c  = ((((r >> 5) + i) & 3) << 1) + kh;   // chunk 0..7
            int kb = (ks << 6) + (c << 3);
            us8 bv;
            if (x_bf16) {
                const unsigned short* xp = (const unsigned short*)X + (size_t)kb * NSP + n0 + r;
                #pragma unroll
                for (int j = 0; j < 8; ++j) bv[j] = xp[(size_t)j * NSP];
            } else {
                const float* xp = (const float*)X + (size_t)kb * NSP + n0 + r;
                #pragma unroll
                for (int j = 0; j < 8; ++j) bv[j] = f2bf(xp[(size_t)j * NSP]);
            }
            int off = (r << 7) + (((c << 4)) ^ ((r & 7) << 4));
            *(us8*)((char*)Bsm + off) = bv;
        }
        __syncthreads();
        // ---- MFMA inner loop
        #pragma unroll
        for (int ki = 0; ki < 2; ++ki) {
            bf16x8 af[4], bfr[4];
            int chunk = (ki << 2) + (lane >> 4);
            #pragma unroll
            for (int m = 0; m < 4; ++m) {
                int row = (wr << 6) + (m << 4) + (lane & 15);
                int off = (row << 7) + (((chunk << 4)) ^ ((row & 7) << 4));
                U8 t; t.u = *(const us8*)((const char*)Asm + off);
                af[m] = t.b;
            }
            #pragma unroll
            for (int n = 0; n < 4; ++n) {
                int row = (wc << 6) + (n << 4) + (lane & 15);
                int off = (row << 7) + (((chunk << 4)) ^ ((row & 7) << 4));
                U8 t; t.u = *(const us8*)((const char*)Bsm + off);
                bfr[n] = t.b;
            }
            #pragma unroll
            for (int m = 0; m < 4; ++m)
                #pragma unroll
                for (int n = 0; n < 4; ++n)
                    acc[m][n] = __builtin_amdgcn_mfma_f32_16x16x32_bf16(af[m], bfr[n], acc[m][n], 0, 0, 0);
        }
        __syncthreads();
    }

    // ---- epilogue: D row=(lane>>4)*4+reg, col=lane&15
    #pragma unroll
    for (int m = 0; m < 4; ++m) {
        #pragma unroll
        for (int reg = 0; reg < 4; ++reg) {
            int o = o0 + (wr << 6) + (m << 4) + ((lane >> 4) << 2) + reg;
            float b = bias[o];
            #pragma unroll
            for (int n = 0; n < 4; ++n) {
                int col = n0 + (wc << 6) + (n << 4) + (lane & 15);
                size_t oi = (size_t)o * NSP + col;
                float v = acc[m][n][reg] + b;
                if (resid) v += resid[oi];
                if (do_relu) v = fmaxf(v, 0.f);
                if (out_bf16) ((unsigned short*)Out)[oi] = f2bf(v);
                else          ((float*)Out)[oi] = v;
            }
        }
    }
}

// ---------------------------------------------------------------------------
// Neighborhood attention: one thread per (group, position). fp32.
// qkv layout: [384][NSP], q = rows 0..127, k = 128..255, v = 256..383
// ---------------------------------------------------------------------------
__global__ __launch_bounds__(256) void attn_kernel(
    const float* __restrict__ qkv, const float* __restrict__ rpb,
    float* __restrict__ sam)
{
    const int g = blockIdx.y;
    const int n = blockIdx.x * 256 + threadIdx.x;
    const int h = n >> 10, w = (n >> 5) & 31, z = n & 31;
    const int ih0 = min(max(h - 1, 0), 29);
    const int iw0 = min(max(w - 1, 0), 29);
    const int iz0 = min(max(z - 1, 0), 29);

    const float* qp = qkv + (g * 16) * NSP + n;
    const float* kbase = qkv + (128 + g * 16) * NSP;
    const float* vbase = qkv + (256 + g * 16) * NSP;

    float q[16];
    #pragma unroll
    for (int d = 0; d < 16; ++d) q[d] = qp[d * NSP];

    float logits[27];
    int idx = 0;
    for (int kh = 0; kh < 3; ++kh)
    for (int kw = 0; kw < 3; ++kw)
    for (int kz = 0; kz < 3; ++kz) {
        int hh = ih0 + kh, ww = iw0 + kw, zz = iz0 + kz;
        int nb = (hh << 10) + (ww << 5) + zz;
        float s = 0.f;
        #pragma unroll
        for (int d = 0; d < 16; ++d) s += q[d] * kbase[d * NSP + nb];
        int rh = hh - h + 2, rw = ww - w + 2, rz = zz - z + 2;
        logits[idx++] = s * 0.25f + rpb[g * 125 + rh * 25 + rw * 5 + rz];
    }

    float mx = -1e30f;
    #pragma unroll
    for (int i = 0; i < 27; ++i) mx = fmaxf(mx, logits[i]);
    float sum = 0.f;
    #pragma unroll
    for (int i = 0; i < 27; ++i) { logits[i] = __expf(logits[i] - mx); sum += logits[i]; }
    float inv = 1.f / sum;

    float out[16] = {};
    idx = 0;
    for (int kh = 0; kh < 3; ++kh)
    for (int kw = 0; kw < 3; ++kw)
    for (int kz = 0; kz < 3; ++kz) {
        int nb = ((ih0 + kh) << 10) + ((iw0 + kw) << 5) + (iz0 + kz);
        float a = logits[idx++] * inv;
        #pragma unroll
        for (int d = 0; d < 16; ++d) out[d] += a * vbase[d * NSP + nb];
    }
    #pragma unroll
    for (int d = 0; d < 16; ++d) sam[(g * 16 + d) * NSP + n] = out[d];
}

// ---------------------------------------------------------------------------
// Instance norm over spatial dims, one block per channel. Optional +x (skip).
// ---------------------------------------------------------------------------
__global__ __launch_bounds__(256) void inorm_kernel(
    const float* __restrict__ in, const float* __restrict__ addx,
    float* __restrict__ out)
{
    const int c = blockIdx.x;
    const float* p = in + (size_t)c * NSP;
    float s = 0.f, ss = 0.f;
    for (int i = threadIdx.x; i < NSP; i += 256) {
        float v = p[i];
        s += v; ss += v * v;
    }
    __shared__ float red[2][4];
    __shared__ float mb, ib;
    for (int off = 32; off > 0; off >>= 1) {
        s  += __shfl_down(s, off);
        ss += __shfl_down(ss, off);
    }
    int wid = threadIdx.x >> 6;
    if ((threadIdx.x & 63) == 0) { red[0][wid] = s; red[1][wid] = ss; }
    __syncthreads();
    if (threadIdx.x == 0) {
        float S  = red[0][0] + red[0][1] + red[0][2] + red[0][3];
        float SS = red[1][0] + red[1][1] + red[1][2] + red[1][3];
        float m = S / NSP;
        float var = SS / NSP - m * m;
        mb = m; ib = rsqrtf(var + EPS);
    }
    __syncthreads();
    float m = mb, inv = ib;
    if (addx) {
        const float* xp = addx + (size_t)c * NSP;
        for (int i = threadIdx.x; i < NSP; i += 256)
            out[(size_t)c * NSP + i] = (p[i] - m) * inv + xp[i];
    } else {
        for (int i = threadIdx.x; i < NSP; i += 256)
            out[(size_t)c * NSP + i] = (p[i] - m) * inv;
    }
}

// ---------------------------------------------------------------------------
// 2x2x2 max pool: 128 * 16^3 outputs
// ---------------------------------------------------------------------------
__global__ __launch_bounds__(256) void pool_kernel(
    const float* __restrict__ skip, float* __restrict__ down)
{
    int m = blockIdx.x * 256 + threadIdx.x;   // < 524288
    int c = m >> 12;
    int r = m & 4095;
    int oh = r >> 8, ow = (r >> 4) & 15, oz = r & 15;
    const float* p = skip + (size_t)c * NSP + (oh * 2) * 1024 + (ow * 2) * 32 + oz * 2;
    float mx = -1e30f;
    #pragma unroll
    for (int dh = 0; dh < 2; ++dh)
    #pragma unroll
    for (int dw = 0; dw < 2; ++dw)
    #pragma unroll
    for (int dz = 0; dz < 2; ++dz)
        mx = fmaxf(mx, p[dh * 1024 + dw * 32 + dz]);
    down[m] = mx;
}

// ---------------------------------------------------------------------------
extern "C" void kernel_launch(void* const* d_in, const int* in_sizes, int n_in,
                              void* d_out, int out_size, void* d_ws, size_t ws_size,
                              hipStream_t stream)
{
    const float* x      = (const float*)d_in[0];
    const float* qkv_w  = (const float*)d_in[1];
    const float* qkv_b  = (const float*)d_in[2];
    const float* proj_w = (const float*)d_in[3];
    const float* proj_b = (const float*)d_in[4];
    const float* rpb    = (const float*)d_in[5];
    const float* w1     = (const float*)d_in[6];
    const float* b1     = (const float*)d_in[7];
    const float* w2     = (const float*)d_in[8];
    const float* b2     = (const float*)d_in[9];

    float* out  = (float*)d_out;
    float* down = out;              // 128*16^3 = 524288 floats (2 MB)
    float* skip = out + 524288;     // 128*32^3

    // Weight stash: the `down` region of d_out is dead until the final pool.
    unsigned short* wb      = (unsigned short*)d_out;
    unsigned short* qkv_sw  = wb;            // 49152 shorts (6 tiles)
    unsigned short* proj_sw = wb + 49152;    // 16384 (2 tiles)
    unsigned short* w1_sw   = wb + 65536;    // 65536 (8 tiles)
    unsigned short* w2_sw   = wb + 131072;   // 65536 (8 tiles)  -> total 384 KB < 2 MB

    char* ws = (char*)d_ws;
    float* qkv    = (float*)(ws);                  // 384*NSP fp32 = 50.3 MB
    float* sam    = (float*)(ws + 50331648);       // 128*NSP fp32 = 16.8 MB
    float* y      = (float*)(ws + 67108864);       // 128*NSP fp32
    float* xn1    = (float*)(ws + 83886080);       // 128*NSP fp32
    unsigned short* hidden = (unsigned short*)ws;  // 512*NSP bf16 = 33.5 MB, overlays dead qkv
    float* t2     = y;                             // overlays dead y

    // 0) weight prep (bf16, pre-swizzled LDS tile images)
    prep_w<<<192, 256, 0, stream>>>(qkv_w, 128, 1, 2, qkv_sw, 49152);
    prep_w<<< 64, 256, 0, stream>>>(proj_w, 128, 1, 2, proj_sw, 16384);
    prep_w<<<256, 256, 0, stream>>>(w1, 1, 512, 2, w1_sw, 65536);   // w1: [K=128][O=512]
    prep_w<<<256, 256, 0, stream>>>(w2, 1, 128, 8, w2_sw, 65536);   // w2: [K=512][O=128]

    // 1) qkv = x @ qkv_w^T + b   (O=384, K=128)
    gemm_mfma<<<dim3(256, 3), 256, 0, stream>>>(qkv_sw, x, qkv_b, nullptr, qkv, 128, 0, 0, 0);
    // 2) neighborhood attention -> sam
    attn_kernel<<<dim3(128, 8), 256, 0, stream>>>(qkv, rpb, sam);
    // 3) proj (O=128, K=128)
    gemm_mfma<<<dim3(256, 1), 256, 0, stream>>>(proj_sw, sam, proj_b, nullptr, y, 128, 0, 0, 0);
    // 4) instance norm 1
    inorm_kernel<<<128, 256, 0, stream>>>(y, nullptr, xn1);
    // 5a) hidden = relu(xn1 @ w1 + b1)  (O=512, K=128), bf16 out
    gemm_mfma<<<dim3(256, 4), 256, 0, stream>>>(w1_sw, xn1, b1, nullptr, hidden, 128, 1, 0, 1);
    // 5b) t2 = xn1 + hidden @ w2 + b2   (O=128, K=512), bf16 in
    gemm_mfma<<<dim3(256, 1), 256, 0, stream>>>(w2_sw, hidden, b2, xn1, t2, 512, 0, 1, 0);
    // 6) instance norm 2 + skip add -> skip
    inorm_kernel<<<128, 256, 0, stream>>>(t2, x, skip);
    // 7) maxpool -> down
    pool_kernel<<<2048, 256, 0, stream>>>(skip, down);
}

// Round 3
// 235.661 us; speedup vs baseline: 2.1964x; 1.4610x over previous
//
#include <hip/hip_runtime.h>

#define NSP 32768   // 32*32*32 spatial positions
#define EPS 1e-5f

typedef __attribute__((ext_vector_type(8))) __bf16 bf16x8;
typedef __attribute__((ext_vector_type(4))) float f32x4;
typedef __attribute__((ext_vector_type(2))) float f32x2;
typedef __attribute__((ext_vector_type(8))) unsigned short us8;
typedef __attribute__((ext_vector_type(4))) unsigned short us4;

union U8 { us8 u; bf16x8 b; };

__device__ __forceinline__ unsigned short f2bf(float f) {
    unsigned u = __float_as_uint(f);
    u += 0x7fff + ((u >> 16) & 1);
    return (unsigned short)(u >> 16);
}
__device__ __forceinline__ float bf2f(unsigned short h) {
    return __uint_as_float(((unsigned)h) << 16);
}

// ---------------------------------------------------------------------------
// Weight prep: fp32 weights (strides sO,sC) -> bf16 pre-swizzled LDS tile
// images for 128(o) x 64(k) tiles. byte = r*128 + ((c*16) ^ ((r&7)<<4)) + 2j
// holds W[ob*128 + r][ks*64 + c*8 + j].
// ---------------------------------------------------------------------------
__global__ __launch_bounds__(256) void prep_w(
    const float* __restrict__ W, int sO, int sC, int ntk,
    unsigned short* __restrict__ Wsw, int total)
{
    int i = blockIdx.x * 256 + threadIdx.x;
    if (i >= total) return;
    int tile = i >> 13;
    int s = i & 8191;
    int r = s >> 6;
    int byte = (s & 63) << 1;
    int ub = byte ^ ((r & 7) << 4);
    int c = ub >> 4;
    int j = (ub >> 1) & 7;
    int ob = tile / ntk;
    int ks = tile - ob * ntk;
    Wsw[i] = f2bf(W[(ob * 128 + r) * sO + (ks * 64 + c * 8 + j) * sC]);
}

// ---------------------------------------------------------------------------
// bf16 MFMA GEMM. Block tile 128(o) x 128(n) x BK=64, 4 waves (2x2), each
// 64x64 via 4x4 mfma_f32_16x16x32_bf16. LDS XOR-swizzled.
// out_mode: 0 = fp32 [o][NSP], 1 = bf16 [o][NSP],
//           2 = transposed bf16 qkv layout [(part*8+g)*NSP + n]*16 + d
// ---------------------------------------------------------------------------
__global__ __launch_bounds__(256) void gemm_mfma(
    const unsigned short* __restrict__ Wsw,
    const void* __restrict__ X,               // [K][NSP] fp32 or bf16
    const float* __restrict__ bias,
    const void* __restrict__ resid,           // fp32/bf16 or null
    void* __restrict__ Out,
    int K, int do_relu, int x_bf16, int out_mode, int resid_bf16)
{
    __shared__ __align__(16) unsigned short smem[16384];   // 32 KB
    unsigned short* Asm = smem;
    unsigned short* Bsm = smem + 8192;
    const int tid  = threadIdx.x;
    const int lane = tid & 63;
    const int wid  = tid >> 6;
    const int wr   = wid >> 1, wc = wid & 1;
    const int n0   = blockIdx.x << 7;
    const int o0   = blockIdx.y << 7;
    const int nk   = K >> 6;

    f32x4 acc[4][4];
    #pragma unroll
    for (int m = 0; m < 4; ++m)
        #pragma unroll
        for (int n = 0; n < 4; ++n)
            acc[m][n] = (f32x4){0.f, 0.f, 0.f, 0.f};

    const int r  = tid & 127;
    const int kh = tid >> 7;

    for (int ks = 0; ks < nk; ++ks) {
        {
            const char* gbase = (const char*)(Wsw + (size_t)(blockIdx.y * nk + ks) * 8192);
            #pragma unroll
            for (int i = 0; i < 4; ++i) {
                us8 v = *(const us8*)(gbase + i * 4096 + tid * 16);
                *(us8*)((char*)Asm + i * 4096 + tid * 16) = v;
            }
        }
        #pragma unroll
        for (int i = 0; i < 4; ++i) {
            int c  = ((((r >> 5) + i) & 3) << 1) + kh;
            int kb = (ks << 6) + (c << 3);
            us8 bv;
            if (x_bf16) {
                const unsigned short* xp = (const unsigned short*)X + (size_t)kb * NSP + n0 + r;
                #pragma unroll
                for (int j = 0; j < 8; ++j) bv[j] = xp[(size_t)j * NSP];
            } else {
                const float* xp = (const float*)X + (size_t)kb * NSP + n0 + r;
                #pragma unroll
                for (int j = 0; j < 8; ++j) bv[j] = f2bf(xp[(size_t)j * NSP]);
            }
            int off = (r << 7) + ((c << 4) ^ ((r & 7) << 4));
            *(us8*)((char*)Bsm + off) = bv;
        }
        __syncthreads();
        #pragma unroll
        for (int ki = 0; ki < 2; ++ki) {
            bf16x8 af[4], bfr[4];
            int chunk = (ki << 2) + (lane >> 4);
            #pragma unroll
            for (int m = 0; m < 4; ++m) {
                int row = (wr << 6) + (m << 4) + (lane & 15);
                int off = (row << 7) + ((chunk << 4) ^ ((row & 7) << 4));
                U8 t; t.u = *(const us8*)((const char*)Asm + off);
                af[m] = t.b;
            }
            #pragma unroll
            for (int n = 0; n < 4; ++n) {
                int row = (wc << 6) + (n << 4) + (lane & 15);
                int off = (row << 7) + ((chunk << 4) ^ ((row & 7) << 4));
                U8 t; t.u = *(const us8*)((const char*)Bsm + off);
                bfr[n] = t.b;
            }
            #pragma unroll
            for (int m = 0; m < 4; ++m)
                #pragma unroll
                for (int n = 0; n < 4; ++n)
                    acc[m][n] = __builtin_amdgcn_mfma_f32_16x16x32_bf16(af[m], bfr[n], acc[m][n], 0, 0, 0);
        }
        __syncthreads();
    }

    if (out_mode == 2) {
        // Transposed bf16 store via per-wave 64x64 LDS tile (swizzled).
        unsigned short* Wt = smem + (wid << 12);
        #pragma unroll
        for (int m = 0; m < 4; ++m)
            #pragma unroll
            for (int reg = 0; reg < 4; ++reg) {
                int ol = (m << 4) + ((lane >> 4) << 2) + reg;
                float b = bias[o0 + (wr << 6) + ol];
                #pragma unroll
                for (int n = 0; n < 4; ++n) {
                    int cl = (n << 4) + (lane & 15);
                    Wt[ol * 64 + (cl ^ ((ol & 7) << 3))] = f2bf(acc[m][n][reg] + b);
                }
            }
        // same-wave LDS: no barrier needed
        const int part = blockIdx.y;
        const int d = lane & 15, coff = lane >> 4;
        unsigned short* O = (unsigned short*)Out;
        #pragma unroll
        for (int go = 0; go < 4; ++go) {
            int g = (wr << 2) + go;
            #pragma unroll
            for (int cc = 0; cc < 16; ++cc) {
                int cl = (cc << 2) + coff;
                int ol = (go << 4) + d;
                unsigned short v = Wt[ol * 64 + (cl ^ ((ol & 7) << 3))];
                size_t idx = ((size_t)((part << 3) + g) * NSP + n0 + (wc << 6) + cl) * 16 + d;
                O[idx] = v;
            }
        }
        return;
    }

    #pragma unroll
    for (int m = 0; m < 4; ++m) {
        #pragma unroll
        for (int reg = 0; reg < 4; ++reg) {
            int o = o0 + (wr << 6) + (m << 4) + ((lane >> 4) << 2) + reg;
            float b = bias[o];
            #pragma unroll
            for (int n = 0; n < 4; ++n) {
                int col = n0 + (wc << 6) + (n << 4) + (lane & 15);
                size_t oi = (size_t)o * NSP + col;
                float v = acc[m][n][reg] + b;
                if (resid) {
                    v += resid_bf16 ? bf2f(((const unsigned short*)resid)[oi])
                                    : ((const float*)resid)[oi];
                }
                if (do_relu) v = fmaxf(v, 0.f);
                if (out_mode == 1) ((unsigned short*)Out)[oi] = f2bf(v);
                else               ((float*)Out)[oi] = v;
            }
        }
    }
}

// ---------------------------------------------------------------------------
// Neighborhood attention on d-contiguous bf16 qkv. One thread per (g, pos).
// qkvT layout: [(part*8+g)][n][16d] bf16, part 0=q,1=k,2=v.
// Output sam bf16 [128][NSP].
// ---------------------------------------------------------------------------
__global__ __launch_bounds__(256) void attn_kernel(
    const unsigned short* __restrict__ qkvT, const float* __restrict__ rpb,
    unsigned short* __restrict__ samb)
{
    const int g = blockIdx.y;
    const int n = blockIdx.x * 256 + threadIdx.x;
    const int h = n >> 10, w = (n >> 5) & 31, z = n & 31;
    const int ih0 = min(max(h - 1, 0), 29);
    const int iw0 = min(max(w - 1, 0), 29);
    const int iz0 = min(max(z - 1, 0), 29);

    const us8* qp = (const us8*)(qkvT + ((size_t)g * NSP + n) * 16);
    const unsigned short* kb = qkvT + (size_t)(8 + g) * NSP * 16;
    const unsigned short* vb = qkvT + (size_t)(16 + g) * NSP * 16;

    float q[16];
    {
        us8 q0 = qp[0], q1 = qp[1];
        #pragma unroll
        for (int j = 0; j < 8; ++j) { q[j] = bf2f(q0[j]); q[8 + j] = bf2f(q1[j]); }
    }

    float logits[27];
    int idx = 0;
    #pragma unroll
    for (int kh = 0; kh < 3; ++kh)
    #pragma unroll
    for (int kw = 0; kw < 3; ++kw)
    #pragma unroll
    for (int kz = 0; kz < 3; ++kz) {
        int hh = ih0 + kh, ww = iw0 + kw, zz = iz0 + kz;
        int nb = (hh << 10) + (ww << 5) + zz;
        const us8* kp = (const us8*)(kb + (size_t)nb * 16);
        us8 k0 = kp[0], k1 = kp[1];
        float s = 0.f;
        #pragma unroll
        for (int j = 0; j < 8; ++j) s += q[j] * bf2f(k0[j]);
        #pragma unroll
        for (int j = 0; j < 8; ++j) s += q[8 + j] * bf2f(k1[j]);
        int rh = hh - h + 2, rw = ww - w + 2, rz = zz - z + 2;
        logits[idx++] = s * 0.25f + rpb[g * 125 + rh * 25 + rw * 5 + rz];
    }

    float mx = -1e30f;
    #pragma unroll
    for (int i = 0; i < 27; ++i) mx = fmaxf(mx, logits[i]);
    float sum = 0.f;
    #pragma unroll
    for (int i = 0; i < 27; ++i) { logits[i] = __expf(logits[i] - mx); sum += logits[i]; }
    float inv = 1.f / sum;

    float o[16] = {};
    idx = 0;
    #pragma unroll
    for (int kh = 0; kh < 3; ++kh)
    #pragma unroll
    for (int kw = 0; kw < 3; ++kw)
    #pragma unroll
    for (int kz = 0; kz < 3; ++kz) {
        int nb = ((ih0 + kh) << 10) + ((iw0 + kw) << 5) + (iz0 + kz);
        const us8* vp = (const us8*)(vb + (size_t)nb * 16);
        us8 v0 = vp[0], v1 = vp[1];
        float a = logits[idx++] * inv;
        #pragma unroll
        for (int j = 0; j < 8; ++j) { o[j] += a * bf2f(v0[j]); o[8 + j] += a * bf2f(v1[j]); }
    }
    #pragma unroll
    for (int d = 0; d < 16; ++d)
        samb[(size_t)(g * 16 + d) * NSP + n] = f2bf(o[d]);
}

// ---------------------------------------------------------------------------
// Instance norm, stage 1: partial sums (8 blocks/channel) -> atomicAdd
// ---------------------------------------------------------------------------
__global__ void zero_sums(float* __restrict__ s) { s[threadIdx.x] = 0.f; }

__global__ __launch_bounds__(256) void inorm_partial(
    const float* __restrict__ in, float* __restrict__ sums)
{
    const int c = blockIdx.x >> 3, seg = blockIdx.x & 7;
    const f32x4* p = (const f32x4*)(in + (size_t)c * NSP + seg * 4096);
    float s = 0.f, ss = 0.f;
    #pragma unroll
    for (int i = 0; i < 4; ++i) {
        f32x4 v = p[threadIdx.x + i * 256];
        s  += v.x + v.y + v.z + v.w;
        ss += v.x * v.x + v.y * v.y + v.z * v.z + v.w * v.w;
    }
    for (int off = 32; off > 0; off >>= 1) {
        s  += __shfl_down(s, off);
        ss += __shfl_down(ss, off);
    }
    __shared__ float red[2][4];
    int wid = threadIdx.x >> 6;
    if ((threadIdx.x & 63) == 0) { red[0][wid] = s; red[1][wid] = ss; }
    __syncthreads();
    if (threadIdx.x == 0) {
        float S  = red[0][0] + red[0][1] + red[0][2] + red[0][3];
        float SS = red[1][0] + red[1][1] + red[1][2] + red[1][3];
        atomicAdd(&sums[c * 2], S);
        atomicAdd(&sums[c * 2 + 1], SS);
    }
}

// ---------------------------------------------------------------------------
// Instance norm apply -> bf16 out (for MLP input / residual)
// ---------------------------------------------------------------------------
__global__ __launch_bounds__(256) void inorm_apply_bf16(
    const float* __restrict__ in, const float* __restrict__ sums,
    unsigned short* __restrict__ out)
{
    size_t i = (size_t)blockIdx.x * 256 + threadIdx.x;   // float4 index
    int c = (int)((i * 4) >> 15);
    float m = sums[c * 2] * (1.f / NSP);
    float var = sums[c * 2 + 1] * (1.f / NSP) - m * m;
    float inv = rsqrtf(var + EPS);
    f32x4 v = ((const f32x4*)in)[i];
    us4 o;
    o.x = f2bf((v.x - m) * inv);
    o.y = f2bf((v.y - m) * inv);
    o.z = f2bf((v.z - m) * inv);
    o.w = f2bf((v.w - m) * inv);
    ((us4*)out)[i] = o;
}

// ---------------------------------------------------------------------------
// Fused: inorm2 apply + skip add + 2x2x2 maxpool.
// One thread per output cube (128 * 16^3 = 524288).
// ---------------------------------------------------------------------------
__global__ __launch_bounds__(256) void inorm_skip_pool(
    const float* __restrict__ t2, const float* __restrict__ x,
    const float* __restrict__ sums,
    float* __restrict__ skip, float* __restrict__ down)
{
    int m = blockIdx.x * 256 + threadIdx.x;
    int c = m >> 12;
    int r = m & 4095;
    int oh = r >> 8, ow = (r >> 4) & 15, oz = r & 15;
    float mean = sums[c * 2] * (1.f / NSP);
    float inv = rsqrtf(sums[c * 2 + 1] * (1.f / NSP) - mean * mean + EPS);
    size_t base = (size_t)c * NSP + oh * 2048 + ow * 64 + oz * 2;
    float mx = -1e30f;
    #pragma unroll
    for (int dh = 0; dh < 2; ++dh)
    #pragma unroll
    for (int dw = 0; dw < 2; ++dw) {
        size_t a = base + dh * 1024 + dw * 32;
        f32x2 tv = *(const f32x2*)(t2 + a);
        f32x2 xv = *(const f32x2*)(x + a);
        f32x2 sv;
        sv.x = (tv.x - mean) * inv + xv.x;
        sv.y = (tv.y - mean) * inv + xv.y;
        *(f32x2*)(skip + a) = sv;
        mx = fmaxf(mx, fmaxf(sv.x, sv.y));
    }
    down[m] = mx;
}

// ---------------------------------------------------------------------------
extern "C" void kernel_launch(void* const* d_in, const int* in_sizes, int n_in,
                              void* d_out, int out_size, void* d_ws, size_t ws_size,
                              hipStream_t stream)
{
    const float* x      = (const float*)d_in[0];
    const float* qkv_w  = (const float*)d_in[1];
    const float* qkv_b  = (const float*)d_in[2];
    const float* proj_w = (const float*)d_in[3];
    const float* proj_b = (const float*)d_in[4];
    const float* rpb    = (const float*)d_in[5];
    const float* w1     = (const float*)d_in[6];
    const float* b1     = (const float*)d_in[7];
    const float* w2     = (const float*)d_in[8];
    const float* b2     = (const float*)d_in[9];

    float* out  = (float*)d_out;
    float* down = out;              // 524288 floats (2 MB), dead until final kernel
    float* skip = out + 524288;

    // Weight stash in the dead `down` region (384 KB < 2 MB)
    unsigned short* wb      = (unsigned short*)d_out;
    unsigned short* qkv_sw  = wb;            // 49152 shorts (6 tiles)
    unsigned short* proj_sw = wb + 49152;    // 16384 (2 tiles)
    unsigned short* w1_sw   = wb + 65536;    // 65536 (8 tiles)
    unsigned short* w2_sw   = wb + 131072;   // 65536 (8 tiles)

    char* ws = (char*)d_ws;
    const size_t MB = 1u << 20;
    unsigned short* qkvT   = (unsigned short*)(ws);            //  0..24 MB
    unsigned short* samb   = (unsigned short*)(ws + 24 * MB);  // 24..32 MB
    float*          y      = (float*)(ws + 32 * MB);           // 32..48 MB
    unsigned short* xn1b   = (unsigned short*)(ws + 48 * MB);  // 48..56 MB
    unsigned short* hidden = (unsigned short*)(ws);            //  0..32 MB (overlays qkvT+samb)
    float*          t2     = (float*)(ws + 56 * MB);           // 56..72 MB
    float*          sums   = (float*)(ws + 72 * MB);           // 512 floats
    float* sums1 = sums;
    float* sums2 = sums + 256;

    // 0) weight prep + zero the reduction accumulators
    prep_w<<<192, 256, 0, stream>>>(qkv_w, 128, 1, 2, qkv_sw, 49152);
    prep_w<<< 64, 256, 0, stream>>>(proj_w, 128, 1, 2, proj_sw, 16384);
    prep_w<<<256, 256, 0, stream>>>(w1, 1, 512, 2, w1_sw, 65536);   // [K=128][O=512]
    prep_w<<<256, 256, 0, stream>>>(w2, 1, 128, 8, w2_sw, 65536);   // [K=512][O=128]
    zero_sums<<<1, 512, 0, stream>>>(sums);

    // 1) qkv = x @ qkv_w^T + b -> transposed bf16 layout
    gemm_mfma<<<dim3(256, 3), 256, 0, stream>>>(qkv_sw, x, qkv_b, nullptr, qkvT, 128, 0, 0, 2, 0);
    // 2) neighborhood attention -> sam (bf16)
    attn_kernel<<<dim3(128, 8), 256, 0, stream>>>(qkvT, rpb, samb);
    // 3) proj (O=128, K=128), bf16 in, fp32 out
    gemm_mfma<<<dim3(256, 1), 256, 0, stream>>>(proj_sw, samb, proj_b, nullptr, y, 128, 0, 1, 0, 0);
    // 4) instance norm 1 -> xn1 (bf16)
    inorm_partial<<<1024, 256, 0, stream>>>(y, sums1);
    inorm_apply_bf16<<<4096, 256, 0, stream>>>(y, sums1, xn1b);
    // 5a) hidden = relu(xn1 @ w1 + b1), bf16 in/out
    gemm_mfma<<<dim3(256, 4), 256, 0, stream>>>(w1_sw, xn1b, b1, nullptr, hidden, 128, 1, 1, 1, 0);
    // 5b) t2 = xn1 + hidden @ w2 + b2, bf16 in, bf16 resid, fp32 out
    gemm_mfma<<<dim3(256, 1), 256, 0, stream>>>(w2_sw, hidden, b2, xn1b, t2, 512, 0, 1, 0, 1);
    // 6) instance norm 2 partial sums
    inorm_partial<<<1024, 256, 0, stream>>>(t2, sums2);
    // 7) fused inorm2 apply + skip + maxpool
    inorm_skip_pool<<<2048, 256, 0, stream>>>(t2, x, sums2, skip, down);
}

// Round 6
// 211.466 us; speedup vs baseline: 2.4477x; 1.1144x over previous
//
#include <hip/hip_runtime.h>

#define NSP 32768   // 32*32*32 spatial positions
#define EPS 1e-5f

typedef __attribute__((ext_vector_type(8))) __bf16 bf16x8;
typedef __attribute__((ext_vector_type(4))) float f32x4;
typedef __attribute__((ext_vector_type(2))) float f32x2;
typedef __attribute__((ext_vector_type(8))) unsigned short us8;
typedef __attribute__((ext_vector_type(4))) unsigned short us4;
typedef __attribute__((ext_vector_type(2))) unsigned short us2;

union U8 { us8 u; bf16x8 b; };

__device__ __forceinline__ unsigned short f2bf(float f) {
    unsigned u = __float_as_uint(f);
    u += 0x7fff + ((u >> 16) & 1);
    return (unsigned short)(u >> 16);
}
__device__ __forceinline__ float bf2f(unsigned short h) {
    return __uint_as_float(((unsigned)h) << 16);
}

// ---------------------------------------------------------------------------
// Weight prep: fp32 weights (strides sO,sC) -> bf16 pre-swizzled LDS tile
// images for 128(o) x 64(k) tiles. byte = r*128 + ((c*16) ^ ((r&7)<<4)) + 2j
// holds W[ob*128 + r][ks*64 + c*8 + j].
// ---------------------------------------------------------------------------
__global__ __launch_bounds__(256) void prep_w(
    const float* __restrict__ W, int sO, int sC, int ntk,
    unsigned short* __restrict__ Wsw, int total)
{
    int i = blockIdx.x * 256 + threadIdx.x;
    if (i >= total) return;
    int tile = i >> 13;
    int s = i & 8191;
    int r = s >> 6;
    int byte = (s & 63) << 1;
    int ub = byte ^ ((r & 7) << 4);
    int c = ub >> 4;
    int j = (ub >> 1) & 7;
    int ob = tile / ntk;
    int ks = tile - ob * ntk;
    Wsw[i] = f2bf(W[(ob * 128 + r) * sO + (ks * 64 + c * 8 + j) * sC]);
}

// ---------------------------------------------------------------------------
// bf16 MFMA GEMM, register-prefetch pipelined (T14-lite).
// Block tile 128(o) x BN(n) x BK=64, 4 waves (2x2).
// out_mode: 0 = fp32 [o][NSP], 1 = bf16 [o][NSP],
//           2 = transposed bf16 qkv layout (BN=128 only)
// ---------------------------------------------------------------------------
template<int BN>
__global__ __launch_bounds__(256) void gemm_mfma(
    const unsigned short* __restrict__ Wsw,
    const void* __restrict__ X,               // [K][NSP] fp32 or bf16
    const float* __restrict__ bias,
    const void* __restrict__ resid,           // fp32/bf16 or null
    void* __restrict__ Out,
    int K, int do_relu, int x_bf16, int out_mode, int resid_bf16)
{
    constexpr int NF = BN / 32;               // n-fragments per wave
    constexpr int BCH = BN / 32;              // B-chunks per thread
    __shared__ __align__(16) unsigned short smem[8192 + BN * 64];
    unsigned short* Asm = smem;
    unsigned short* Bsm = smem + 8192;
    const int tid  = threadIdx.x;
    const int lane = tid & 63;
    const int wid  = tid >> 6;
    const int wr   = wid >> 1, wc = wid & 1;
    const int n0   = blockIdx.x * BN;
    const int o0   = blockIdx.y << 7;
    const int nk   = K >> 6;

    f32x4 acc[4][NF];
    #pragma unroll
    for (int m = 0; m < 4; ++m)
        #pragma unroll
        for (int n = 0; n < NF; ++n)
            acc[m][n] = (f32x4){0.f, 0.f, 0.f, 0.f};

    const int r  = (BN == 128) ? (tid & 127) : (tid & 63);
    const int kh = (BN == 128) ? (tid >> 7)  : (tid >> 6);

    us8 a_pre[4];
    us8 b_pre[BCH];
    int b_c[BCH];
    #pragma unroll
    for (int i = 0; i < BCH; ++i)
        b_c[i] = (BN == 128) ? (((((r >> 5) + i) & 3) << 1) + kh)
                             : (((((r >> 4) + i) & 1) << 2) + kh);

    auto load_tile = [&](int ks) {
        const char* gbase = (const char*)(Wsw + (size_t)(blockIdx.y * nk + ks) * 8192);
        #pragma unroll
        for (int i = 0; i < 4; ++i)
            a_pre[i] = *(const us8*)(gbase + i * 4096 + tid * 16);
        #pragma unroll
        for (int i = 0; i < BCH; ++i) {
            int kb = (ks << 6) + (b_c[i] << 3);
            us8 bv;
            if (x_bf16) {
                const unsigned short* xp = (const unsigned short*)X + (size_t)kb * NSP + n0 + r;
                #pragma unroll
                for (int j = 0; j < 8; ++j) bv[j] = xp[(size_t)j * NSP];
            } else {
                const float* xp = (const float*)X + (size_t)kb * NSP + n0 + r;
                #pragma unroll
                for (int j = 0; j < 8; ++j) bv[j] = f2bf(xp[(size_t)j * NSP]);
            }
            b_pre[i] = bv;
        }
    };
    auto store_tile = [&]() {
        #pragma unroll
        for (int i = 0; i < 4; ++i)
            *(us8*)((char*)Asm + i * 4096 + tid * 16) = a_pre[i];
        #pragma unroll
        for (int i = 0; i < BCH; ++i) {
            int off = (r << 7) + ((b_c[i] << 4) ^ ((r & 7) << 4));
            *(us8*)((char*)Bsm + off) = b_pre[i];
        }
    };

    load_tile(0);
    store_tile();
    __syncthreads();

    for (int ks = 0; ks < nk; ++ks) {
        if (ks + 1 < nk) load_tile(ks + 1);   // loads in flight during MFMA
        #pragma unroll
        for (int ki = 0; ki < 2; ++ki) {
            bf16x8 af[4], bfr[NF];
            int chunk = (ki << 2) + (lane >> 4);
            #pragma unroll
            for (int m = 0; m < 4; ++m) {
                int row = (wr << 6) + (m << 4) + (lane & 15);
                int off = (row << 7) + ((chunk << 4) ^ ((row & 7) << 4));
                U8 t; t.u = *(const us8*)((const char*)Asm + off);
                af[m] = t.b;
            }
            #pragma unroll
            for (int n = 0; n < NF; ++n) {
                int row = wc * (BN / 2) + (n << 4) + (lane & 15);
                int off = (row << 7) + ((chunk << 4) ^ ((row & 7) << 4));
                U8 t; t.u = *(const us8*)((const char*)Bsm + off);
                bfr[n] = t.b;
            }
            #pragma unroll
            for (int m = 0; m < 4; ++m)
                #pragma unroll
                for (int n = 0; n < NF; ++n)
                    acc[m][n] = __builtin_amdgcn_mfma_f32_16x16x32_bf16(af[m], bfr[n], acc[m][n], 0, 0, 0);
        }
        if (ks + 1 < nk) {
            __syncthreads();
            store_tile();
            __syncthreads();
        }
    }

    if (BN == 128 && out_mode == 2) {
        __syncthreads();   // all waves done with Asm/Bsm before reuse
        unsigned short* Wt = smem + (wid << 12);
        #pragma unroll
        for (int m = 0; m < 4; ++m)
            #pragma unroll
            for (int reg = 0; reg < 4; ++reg) {
                int ol = (m << 4) + ((lane >> 4) << 2) + reg;
                float b = bias[o0 + (wr << 6) + ol];
                #pragma unroll
                for (int n = 0; n < NF; ++n) {
                    int cl = (n << 4) + (lane & 15);
                    Wt[ol * 64 + (cl ^ ((ol & 7) << 3))] = f2bf(acc[m][n][reg] + b);
                }
            }
        const int part = blockIdx.y;
        const int d = lane & 15, coff = lane >> 4;
        unsigned short* O = (unsigned short*)Out;
        #pragma unroll
        for (int go = 0; go < 4; ++go) {
            int g = (wr << 2) + go;
            #pragma unroll
            for (int cc = 0; cc < 16; ++cc) {
                int cl = (cc << 2) + coff;
                int ol = (go << 4) + d;
                unsigned short v = Wt[ol * 64 + (cl ^ ((ol & 7) << 3))];
                size_t idx = ((size_t)((part << 3) + g) * NSP + n0 + (wc << 6) + cl) * 16 + d;
                O[idx] = v;
            }
        }
        return;
    }

    #pragma unroll
    for (int m = 0; m < 4; ++m) {
        #pragma unroll
        for (int reg = 0; reg < 4; ++reg) {
            int o = o0 + (wr << 6) + (m << 4) + ((lane >> 4) << 2) + reg;
            float b = bias[o];
            #pragma unroll
            for (int n = 0; n < NF; ++n) {
                int col = n0 + wc * (BN / 2) + (n << 4) + (lane & 15);
                size_t oi = (size_t)o * NSP + col;
                float v = acc[m][n][reg] + b;
                if (resid) {
                    v += resid_bf16 ? bf2f(((const unsigned short*)resid)[oi])
                                    : ((const float*)resid)[oi];
                }
                if (do_relu) v = fmaxf(v, 0.f);
                if (out_mode == 1) ((unsigned short*)Out)[oi] = f2bf(v);
                else               ((float*)Out)[oi] = v;
            }
        }
    }
}

// ---------------------------------------------------------------------------
// Neighborhood attention on d-contiguous bf16 qkv. One thread per (g, pos).
// ---------------------------------------------------------------------------
__global__ __launch_bounds__(256) void attn_kernel(
    const unsigned short* __restrict__ qkvT, const float* __restrict__ rpb,
    unsigned short* __restrict__ samb)
{
    const int g = blockIdx.y;
    const int n = blockIdx.x * 256 + threadIdx.x;
    const int h = n >> 10, w = (n >> 5) & 31, z = n & 31;
    const int ih0 = min(max(h - 1, 0), 29);
    const int iw0 = min(max(w - 1, 0), 29);
    const int iz0 = min(max(z - 1, 0), 29);

    const us8* qp = (const us8*)(qkvT + ((size_t)g * NSP + n) * 16);
    const unsigned short* kb = qkvT + (size_t)(8 + g) * NSP * 16;
    const unsigned short* vb = qkvT + (size_t)(16 + g) * NSP * 16;

    float q[16];
    {
        us8 q0 = qp[0], q1 = qp[1];
        #pragma unroll
        for (int j = 0; j < 8; ++j) { q[j] = bf2f(q0[j]); q[8 + j] = bf2f(q1[j]); }
    }

    float logits[27];
    int idx = 0;
    #pragma unroll
    for (int kh = 0; kh < 3; ++kh)
    #pragma unroll
    for (int kw = 0; kw < 3; ++kw)
    #pragma unroll
    for (int kz = 0; kz < 3; ++kz) {
        int hh = ih0 + kh, ww = iw0 + kw, zz = iz0 + kz;
        int nb = (hh << 10) + (ww << 5) + zz;
        const us8* kp = (const us8*)(kb + (size_t)nb * 16);
        us8 k0 = kp[0], k1 = kp[1];
        float s = 0.f;
        #pragma unroll
        for (int j = 0; j < 8; ++j) s += q[j] * bf2f(k0[j]);
        #pragma unroll
        for (int j = 0; j < 8; ++j) s += q[8 + j] * bf2f(k1[j]);
        int rh = hh - h + 2, rw = ww - w + 2, rz = zz - z + 2;
        logits[idx++] = s * 0.25f + rpb[g * 125 + rh * 25 + rw * 5 + rz];
    }

    float mx = -1e30f;
    #pragma unroll
    for (int i = 0; i < 27; ++i) mx = fmaxf(mx, logits[i]);
    float sum = 0.f;
    #pragma unroll
    for (int i = 0; i < 27; ++i) { logits[i] = __expf(logits[i] - mx); sum += logits[i]; }
    float inv = 1.f / sum;

    float o[16] = {};
    idx = 0;
    #pragma unroll
    for (int kh = 0; kh < 3; ++kh)
    #pragma unroll
    for (int kw = 0; kw < 3; ++kw)
    #pragma unroll
    for (int kz = 0; kz < 3; ++kz) {
        int nb = ((ih0 + kh) << 10) + ((iw0 + kw) << 5) + (iz0 + kz);
        const us8* vp = (const us8*)(vb + (size_t)nb * 16);
        us8 v0 = vp[0], v1 = vp[1];
        float a = logits[idx++] * inv;
        #pragma unroll
        for (int j = 0; j < 8; ++j) { o[j] += a * bf2f(v0[j]); o[8 + j] += a * bf2f(v1[j]); }
    }
    #pragma unroll
    for (int d = 0; d < 16; ++d)
        samb[(size_t)(g * 16 + d) * NSP + n] = f2bf(o[d]);
}

// ---------------------------------------------------------------------------
__global__ void zero_sums(float* __restrict__ s) { s[threadIdx.x] = 0.f; }

// Instance norm partials from bf16 input (8 blocks/channel)
__global__ __launch_bounds__(256) void inorm_partial_bf16(
    const unsigned short* __restrict__ in, float* __restrict__ sums)
{
    const int c = blockIdx.x >> 3, seg = blockIdx.x & 7;
    const us8* p = (const us8*)(in + (size_t)c * NSP + seg * 4096);
    float s = 0.f, ss = 0.f;
    #pragma unroll
    for (int i = 0; i < 2; ++i) {
        us8 v = p[threadIdx.x + i * 256];
        #pragma unroll
        for (int j = 0; j < 8; ++j) { float f = bf2f(v[j]); s += f; ss += f * f; }
    }
    for (int off = 32; off > 0; off >>= 1) {
        s  += __shfl_down(s, off);
        ss += __shfl_down(ss, off);
    }
    __shared__ float red[2][4];
    int wid = threadIdx.x >> 6;
    if ((threadIdx.x & 63) == 0) { red[0][wid] = s; red[1][wid] = ss; }
    __syncthreads();
    if (threadIdx.x == 0) {
        atomicAdd(&sums[c * 2],     red[0][0] + red[0][1] + red[0][2] + red[0][3]);
        atomicAdd(&sums[c * 2 + 1], red[1][0] + red[1][1] + red[1][2] + red[1][3]);
    }
}

// Instance norm apply: bf16 in -> bf16 out
__global__ __launch_bounds__(256) void inorm_apply_bf16(
    const unsigned short* __restrict__ in, const float* __restrict__ sums,
    unsigned short* __restrict__ out)
{
    size_t i = (size_t)blockIdx.x * 256 + threadIdx.x;   // us8 index
    int c = (int)((i * 8) >> 15);
    float m = sums[c * 2] * (1.f / NSP);
    float var = sums[c * 2 + 1] * (1.f / NSP) - m * m;
    float inv = rsqrtf(var + EPS);
    us8 v = ((const us8*)in)[i];
    us8 o;
    #pragma unroll
    for (int j = 0; j < 8; ++j) o[j] = f2bf((bf2f(v[j]) - m) * inv);
    ((us8*)out)[i] = o;
}

// Fused: inorm2 apply (bf16 in) + skip add (fp32 x) + 2x2x2 maxpool.
__global__ __launch_bounds__(256) void inorm_skip_pool(
    const unsigned short* __restrict__ t2, const float* __restrict__ x,
    const float* __restrict__ sums,
    float* __restrict__ skip, float* __restrict__ down)
{
    int m = blockIdx.x * 256 + threadIdx.x;
    int c = m >> 12;
    int r = m & 4095;
    int oh = r >> 8, ow = (r >> 4) & 15, oz = r & 15;
    float mean = sums[c * 2] * (1.f / NSP);
    float inv = rsqrtf(sums[c * 2 + 1] * (1.f / NSP) - mean * mean + EPS);
    size_t base = (size_t)c * NSP + oh * 2048 + ow * 64 + oz * 2;
    float mx = -1e30f;
    #pragma unroll
    for (int dh = 0; dh < 2; ++dh)
    #pragma unroll
    for (int dw = 0; dw < 2; ++dw) {
        size_t a = base + dh * 1024 + dw * 32;
        us2 tv = *(const us2*)(t2 + a);
        f32x2 xv = *(const f32x2*)(x + a);
        f32x2 sv;
        sv.x = (bf2f(tv.x) - mean) * inv + xv.x;
        sv.y = (bf2f(tv.y) - mean) * inv + xv.y;
        *(f32x2*)(skip + a) = sv;
        mx = fmaxf(mx, fmaxf(sv.x, sv.y));
    }
    down[m] = mx;
}

// ---------------------------------------------------------------------------
extern "C" void kernel_launch(void* const* d_in, const int* in_sizes, int n_in,
                              void* d_out, int out_size, void* d_ws, size_t ws_size,
                              hipStream_t stream)
{
    const float* x      = (const float*)d_in[0];
    const float* qkv_w  = (const float*)d_in[1];
    const float* qkv_b  = (const float*)d_in[2];
    const float* proj_w = (const float*)d_in[3];
    const float* proj_b = (const float*)d_in[4];
    const float* rpb    = (const float*)d_in[5];
    const float* w1     = (const float*)d_in[6];
    const float* b1     = (const float*)d_in[7];
    const float* w2     = (const float*)d_in[8];
    const float* b2     = (const float*)d_in[9];

    float* out  = (float*)d_out;
    float* down = out;              // 2 MB, dead until final kernel
    float* skip = out + 524288;

    // Weight stash in the dead `down` region (384 KB < 2 MB)
    unsigned short* wb      = (unsigned short*)d_out;
    unsigned short* qkv_sw  = wb;
    unsigned short* proj_sw = wb + 49152;
    unsigned short* w1_sw   = wb + 65536;
    unsigned short* w2_sw   = wb + 131072;

    char* ws = (char*)d_ws;
    const size_t MB = 1u << 20;
    unsigned short* qkvT   = (unsigned short*)(ws);            //  0..24 MB
    unsigned short* samb   = (unsigned short*)(ws + 24 * MB);  // 24..32 MB
    unsigned short* yb     = (unsigned short*)(ws + 32 * MB);  // 32..40 MB
    unsigned short* xn1b   = (unsigned short*)(ws + 40 * MB);  // 40..48 MB
    unsigned short* hidden = (unsigned short*)(ws);            //  0..32 MB (overlays qkvT+samb)
    unsigned short* t2b    = (unsigned short*)(ws + 48 * MB);  // 48..56 MB
    float*          sums   = (float*)(ws + 72 * MB);
    float* sums1 = sums;
    float* sums2 = sums + 256;

    prep_w<<<192, 256, 0, stream>>>(qkv_w, 128, 1, 2, qkv_sw, 49152);
    prep_w<<< 64, 256, 0, stream>>>(proj_w, 128, 1, 2, proj_sw, 16384);
    prep_w<<<256, 256, 0, stream>>>(w1, 1, 512, 2, w1_sw, 65536);
    prep_w<<<256, 256, 0, stream>>>(w2, 1, 128, 8, w2_sw, 65536);
    zero_sums<<<1, 512, 0, stream>>>(sums);

    // 1) qkv -> transposed bf16 layout
    gemm_mfma<128><<<dim3(256, 3), 256, 0, stream>>>(qkv_sw, x, qkv_b, nullptr, qkvT, 128, 0, 0, 2, 0);
    // 2) attention
    attn_kernel<<<dim3(128, 8), 256, 0, stream>>>(qkvT, rpb, samb);
    // 3) proj (O=128, K=128) bf16 in/out, BN=64 grid 512
    gemm_mfma<64><<<dim3(512, 1), 256, 0, stream>>>(proj_sw, samb, proj_b, nullptr, yb, 128, 0, 1, 1, 0);
    // 4) instance norm 1 -> xn1 bf16
    inorm_partial_bf16<<<1024, 256, 0, stream>>>(yb, sums1);
    inorm_apply_bf16<<<2048, 256, 0, stream>>>(yb, sums1, xn1b);
    // 5a) hidden = relu(xn1 @ w1 + b1)
    gemm_mfma<128><<<dim3(256, 4), 256, 0, stream>>>(w1_sw, xn1b, b1, nullptr, hidden, 128, 1, 1, 1, 0);
    // 5b) t2 = xn1 + hidden @ w2 + b2, BN=64 grid 512, bf16 out
    gemm_mfma<64><<<dim3(512, 1), 256, 0, stream>>>(w2_sw, hidden, b2, xn1b, t2b, 512, 0, 1, 1, 1);
    // 6) instance norm 2 partials
    inorm_partial_bf16<<<1024, 256, 0, stream>>>(t2b, sums2);
    // 7) fused inorm2 apply + skip + maxpool
    inorm_skip_pool<<<2048, 256, 0, stream>>>(t2b, x, sums2, skip, down);
}

// Round 9
// 191.017 us; speedup vs baseline: 2.7098x; 1.1071x over previous
//
#include <hip/hip_runtime.h>

#define NSP 32768   // 32*32*32 spatial positions
#define EPS 1e-5f

typedef __attribute__((ext_vector_type(8))) __bf16 bf16x8;
typedef __attribute__((ext_vector_type(4))) float f32x4;
typedef __attribute__((ext_vector_type(2))) float f32x2;
typedef __attribute__((ext_vector_type(8))) unsigned short us8;
typedef __attribute__((ext_vector_type(2))) unsigned short us2;

union U8 { us8 u; bf16x8 b; };

__device__ __forceinline__ unsigned short f2bf(float f) {
    unsigned u = __float_as_uint(f);
    u += 0x7fff + ((u >> 16) & 1);
    return (unsigned short)(u >> 16);
}
__device__ __forceinline__ float bf2f(unsigned short h) {
    return __uint_as_float(((unsigned)h) << 16);
}

// ---------------------------------------------------------------------------
// Weight prep (all 4 weights + zero sums in ONE kernel).
// bf16 pre-swizzled LDS tile images for 128(o) x 64(k) tiles.
// byte = r*128 + ((c*16) ^ ((r&7)<<4)) + 2j holds W[ob*128+r][ks*64+c*8+j].
// ---------------------------------------------------------------------------
__device__ __forceinline__ void prep_range(
    const float* __restrict__ W, int sO, int sC, int ntk,
    unsigned short* __restrict__ Wsw, int i)
{
    int tile = i >> 13;
    int s = i & 8191;
    int r = s >> 6;
    int byte = (s & 63) << 1;
    int ub = byte ^ ((r & 7) << 4);
    int c = ub >> 4;
    int j = (ub >> 1) & 7;
    int ob = tile / ntk;
    int ks = tile - ob * ntk;
    Wsw[i] = f2bf(W[(ob * 128 + r) * sO + (ks * 64 + c * 8 + j) * sC]);
}

__global__ __launch_bounds__(256) void prep_all(
    const float* __restrict__ qkv_w, const float* __restrict__ proj_w,
    const float* __restrict__ w1, const float* __restrict__ w2,
    unsigned short* __restrict__ qkv_sw, unsigned short* __restrict__ proj_sw,
    unsigned short* __restrict__ w1_sw, unsigned short* __restrict__ w2_sw,
    float* __restrict__ sums)
{
    int bid = blockIdx.x, tid = threadIdx.x;
    if (bid < 192)       prep_range(qkv_w, 128, 1, 2, qkv_sw, bid * 256 + tid);
    else if (bid < 256)  prep_range(proj_w, 128, 1, 2, proj_sw, (bid - 192) * 256 + tid);
    else if (bid < 512)  prep_range(w1, 1, 512, 2, w1_sw, (bid - 256) * 256 + tid);
    else if (bid < 768)  prep_range(w2, 1, 128, 8, w2_sw, (bid - 512) * 256 + tid);
    else { sums[tid] = 0.f; sums[tid + 256] = 0.f; }
}

// ---------------------------------------------------------------------------
// bf16 MFMA GEMM, register-prefetch pipelined.
// Block tile 128(o) x BN(n) x BK=64, 4 waves (2x2).
// XMODE: 0 = fp32 [k][NSP]; 2 = bf16 rows [n][RW] (vector chunk load);
//        3 = bf16 [k][NSP] + on-the-fly norm via table
// OMODE: 1 = bf16 [o][NSP]; 2 = qkvT layout; 3 = bf16 rows [n][RW2]
// ---------------------------------------------------------------------------
template<int BN, int XMODE, int OMODE>
__global__ __launch_bounds__(256) void gemm_mfma(
    const unsigned short* __restrict__ Wsw,
    const void* __restrict__ X,
    const float* __restrict__ bias,
    const unsigned short* __restrict__ resid,   // bf16 [o][NSP] or null
    const f32x2* __restrict__ table,            // norm table (XMODE3 / resid-norm)
    void* __restrict__ Out,
    int K, int do_relu, int rw)                 // rw: row width for XMODE2/OMODE3
{
    constexpr int NF = BN / 32;
    constexpr int BCH = BN / 32;
    __shared__ __align__(16) unsigned short smem[8192 + BN * 64];
    unsigned short* Asm = smem;
    unsigned short* Bsm = smem + 8192;
    const int tid  = threadIdx.x;
    const int lane = tid & 63;
    const int wid  = tid >> 6;
    const int wr   = wid >> 1, wc = wid & 1;
    const int n0   = blockIdx.x * BN;
    const int o0   = blockIdx.y << 7;
    const int nk   = K >> 6;

    f32x4 acc[4][NF];
    #pragma unroll
    for (int m = 0; m < 4; ++m)
        #pragma unroll
        for (int n = 0; n < NF; ++n)
            acc[m][n] = (f32x4){0.f, 0.f, 0.f, 0.f};

    const int r  = (BN == 128) ? (tid & 127) : (tid & 63);
    const int kh = (BN == 128) ? (tid >> 7)  : (tid >> 6);

    us8 a_pre[4];
    us8 b_pre[BCH];
    int b_c[BCH];
    #pragma unroll
    for (int i = 0; i < BCH; ++i)
        b_c[i] = (BN == 128) ? (((((r >> 5) + i) & 3) << 1) + kh)
                             : (((((r >> 4) + i) & 1) << 2) + kh);

    auto load_tile = [&](int ks) {
        const char* gbase = (const char*)(Wsw + (size_t)(blockIdx.y * nk + ks) * 8192);
        #pragma unroll
        for (int i = 0; i < 4; ++i)
            a_pre[i] = *(const us8*)(gbase + i * 4096 + tid * 16);
        #pragma unroll
        for (int i = 0; i < BCH; ++i) {
            int c = b_c[i];
            int kb = (ks << 6) + (c << 3);
            us8 bv;
            if (XMODE == 0) {
                const float* xp = (const float*)X + (size_t)kb * NSP + n0 + r;
                #pragma unroll
                for (int j = 0; j < 8; ++j) bv[j] = f2bf(xp[(size_t)j * NSP]);
            } else if (XMODE == 2) {
                bv = *(const us8*)((const unsigned short*)X + (size_t)(n0 + r) * rw + kb);
            } else {  // XMODE 3: bf16 [k][NSP] + norm
                const unsigned short* xp = (const unsigned short*)X + (size_t)kb * NSP + n0 + r;
                #pragma unroll
                for (int j = 0; j < 8; ++j) {
                    f32x2 t = table[kb + j];
                    bv[j] = f2bf((bf2f(xp[(size_t)j * NSP]) - t.x) * t.y);
                }
            }
            b_pre[i] = bv;
        }
    };
    auto store_tile = [&]() {
        #pragma unroll
        for (int i = 0; i < 4; ++i)
            *(us8*)((char*)Asm + i * 4096 + tid * 16) = a_pre[i];
        #pragma unroll
        for (int i = 0; i < BCH; ++i) {
            int off = (r << 7) + ((b_c[i] << 4) ^ ((r & 7) << 4));
            *(us8*)((char*)Bsm + off) = b_pre[i];
        }
    };

    load_tile(0);
    store_tile();
    __syncthreads();

    for (int ks = 0; ks < nk; ++ks) {
        if (ks + 1 < nk) load_tile(ks + 1);   // next tile's loads in flight during MFMA
        #pragma unroll
        for (int ki = 0; ki < 2; ++ki) {
            bf16x8 af[4], bfr[NF];
            int chunk = (ki << 2) + (lane >> 4);
            #pragma unroll
            for (int m = 0; m < 4; ++m) {
                int row = (wr << 6) + (m << 4) + (lane & 15);
                int off = (row << 7) + ((chunk << 4) ^ ((row & 7) << 4));
                U8 t; t.u = *(const us8*)((const char*)Asm + off);
                af[m] = t.b;
            }
            #pragma unroll
            for (int n = 0; n < NF; ++n) {
                int row = wc * (BN / 2) + (n << 4) + (lane & 15);
                int off = (row << 7) + ((chunk << 4) ^ ((row & 7) << 4));
                U8 t; t.u = *(const us8*)((const char*)Bsm + off);
                bfr[n] = t.b;
            }
            #pragma unroll
            for (int m = 0; m < 4; ++m)
                #pragma unroll
                for (int n = 0; n < NF; ++n)
                    acc[m][n] = __builtin_amdgcn_mfma_f32_16x16x32_bf16(af[m], bfr[n], acc[m][n], 0, 0, 0);
        }
        if (ks + 1 < nk) {
            __syncthreads();
            store_tile();
            __syncthreads();
        }
    }

    if (OMODE == 2 || OMODE == 3) {
        // Transposed store via per-wave 64x64 LDS tile (swizzled).
        __syncthreads();
        unsigned short* Wt = smem + (wid << 12);
        #pragma unroll
        for (int m = 0; m < 4; ++m)
            #pragma unroll
            for (int reg = 0; reg < 4; ++reg) {
                int ol = (m << 4) + ((lane >> 4) << 2) + reg;
                float b = bias[o0 + (wr << 6) + ol];
                #pragma unroll
                for (int n = 0; n < NF; ++n) {
                    int cl = (n << 4) + (lane & 15);
                    float v = acc[m][n][reg] + b;
                    if (do_relu) v = fmaxf(v, 0.f);
                    Wt[ol * 64 + (cl ^ ((ol & 7) << 3))] = f2bf(v);
                }
            }
        const int d = lane & 15, coff = lane >> 4;
        unsigned short* O = (unsigned short*)Out;
        #pragma unroll
        for (int go = 0; go < 4; ++go) {
            #pragma unroll
            for (int cc = 0; cc < 16; ++cc) {
                int cl = (cc << 2) + coff;
                int ol = (go << 4) + d;
                unsigned short v = Wt[ol * 64 + (cl ^ ((ol & 7) << 3))];
                size_t idx;
                if (OMODE == 2) {
                    int g = (wr << 2) + go;   // part = blockIdx.y
                    idx = ((size_t)((blockIdx.y << 3) + g) * NSP + n0 + (wc << 6) + cl) * 16 + d;
                } else {
                    idx = (size_t)(n0 + (wc << 6) + cl) * rw + o0 + (wr << 6) + (go << 4) + d;
                }
                O[idx] = v;
            }
        }
        return;
    }

    // OMODE 1: bf16 [o][NSP] with optional (normalized) residual
    #pragma unroll
    for (int m = 0; m < 4; ++m) {
        #pragma unroll
        for (int reg = 0; reg < 4; ++reg) {
            int o = o0 + (wr << 6) + (m << 4) + ((lane >> 4) << 2) + reg;
            float b = bias[o];
            f32x2 rt = resid ? table[o] : (f32x2){0.f, 1.f};
            #pragma unroll
            for (int n = 0; n < NF; ++n) {
                int col = n0 + wc * (BN / 2) + (n << 4) + (lane & 15);
                size_t oi = (size_t)o * NSP + col;
                float v = acc[m][n][reg] + b;
                if (resid) v += (bf2f(resid[oi]) - rt.x) * rt.y;
                if (do_relu) v = fmaxf(v, 0.f);
                ((unsigned short*)Out)[oi] = f2bf(v);
            }
        }
    }
}

// ---------------------------------------------------------------------------
// Neighborhood attention on d-contiguous bf16 qkv. One thread per (g, pos).
// Output samT [n][128] bf16 (d-contiguous row-major).
// ---------------------------------------------------------------------------
__global__ __launch_bounds__(256) void attn_kernel(
    const unsigned short* __restrict__ qkvT, const float* __restrict__ rpb,
    unsigned short* __restrict__ samT)
{
    const int g = blockIdx.y;
    const int n = blockIdx.x * 256 + threadIdx.x;
    const int h = n >> 10, w = (n >> 5) & 31, z = n & 31;
    const int ih0 = min(max(h - 1, 0), 29);
    const int iw0 = min(max(w - 1, 0), 29);
    const int iz0 = min(max(z - 1, 0), 29);

    const us8* qp = (const us8*)(qkvT + ((size_t)g * NSP + n) * 16);
    const unsigned short* kb = qkvT + (size_t)(8 + g) * NSP * 16;
    const unsigned short* vb = qkvT + (size_t)(16 + g) * NSP * 16;

    float q[16];
    {
        us8 q0 = qp[0], q1 = qp[1];
        #pragma unroll
        for (int j = 0; j < 8; ++j) { q[j] = bf2f(q0[j]); q[8 + j] = bf2f(q1[j]); }
    }

    float logits[27];
    int idx = 0;
    #pragma unroll
    for (int kh = 0; kh < 3; ++kh)
    #pragma unroll
    for (int kw = 0; kw < 3; ++kw)
    #pragma unroll
    for (int kz = 0; kz < 3; ++kz) {
        int hh = ih0 + kh, ww = iw0 + kw, zz = iz0 + kz;
        int nb = (hh << 10) + (ww << 5) + zz;
        const us8* kp = (const us8*)(kb + (size_t)nb * 16);
        us8 k0 = kp[0], k1 = kp[1];
        float s = 0.f;
        #pragma unroll
        for (int j = 0; j < 8; ++j) s += q[j] * bf2f(k0[j]);
        #pragma unroll
        for (int j = 0; j < 8; ++j) s += q[8 + j] * bf2f(k1[j]);
        int rh = hh - h + 2, rw = ww - w + 2, rz = zz - z + 2;
        logits[idx++] = s * 0.25f + rpb[g * 125 + rh * 25 + rw * 5 + rz];
    }

    float mx = -1e30f;
    #pragma unroll
    for (int i = 0; i < 27; ++i) mx = fmaxf(mx, logits[i]);
    float sum = 0.f;
    #pragma unroll
    for (int i = 0; i < 27; ++i) { logits[i] = __expf(logits[i] - mx); sum += logits[i]; }
    float inv = 1.f / sum;

    float o[16] = {};
    idx = 0;
    #pragma unroll
    for (int kh = 0; kh < 3; ++kh)
    #pragma unroll
    for (int kw = 0; kw < 3; ++kw)
    #pragma unroll
    for (int kz = 0; kz < 3; ++kz) {
        int nb = ((ih0 + kh) << 10) + ((iw0 + kw) << 5) + (iz0 + kz);
        const us8* vp = (const us8*)(vb + (size_t)nb * 16);
        us8 v0 = vp[0], v1 = vp[1];
        float a = logits[idx++] * inv;
        #pragma unroll
        for (int j = 0; j < 8; ++j) { o[j] += a * bf2f(v0[j]); o[8 + j] += a * bf2f(v1[j]); }
    }
    us8 o0v, o1v;
    #pragma unroll
    for (int j = 0; j < 8; ++j) { o0v[j] = f2bf(o[j]); o1v[j] = f2bf(o[8 + j]); }
    us8* op = (us8*)(samT + (size_t)n * 128 + g * 16);
    op[0] = o0v; op[1] = o1v;
}

// ---------------------------------------------------------------------------
// Instance norm partials from bf16 [c][n] input (8 blocks/channel)
// ---------------------------------------------------------------------------
__global__ __launch_bounds__(256) void inorm_partial_bf16(
    const unsigned short* __restrict__ in, float* __restrict__ sums)
{
    const int c = blockIdx.x >> 3, seg = blockIdx.x & 7;
    const us8* p = (const us8*)(in + (size_t)c * NSP + seg * 4096);
    float s = 0.f, ss = 0.f;
    #pragma unroll
    for (int i = 0; i < 2; ++i) {
        us8 v = p[threadIdx.x + i * 256];
        #pragma unroll
        for (int j = 0; j < 8; ++j) { float f = bf2f(v[j]); s += f; ss += f * f; }
    }
    for (int off = 32; off > 0; off >>= 1) {
        s  += __shfl_down(s, off);
        ss += __shfl_down(ss, off);
    }
    __shared__ float red[2][4];
    int wid = threadIdx.x >> 6;
    if ((threadIdx.x & 63) == 0) { red[0][wid] = s; red[1][wid] = ss; }
    __syncthreads();
    if (threadIdx.x == 0) {
        atomicAdd(&sums[c * 2],     red[0][0] + red[0][1] + red[0][2] + red[0][3]);
        atomicAdd(&sums[c * 2 + 1], red[1][0] + red[1][1] + red[1][2] + red[1][3]);
    }
}

// sums -> (mean, rsqrt(var+eps)) table
__global__ void finalize_sums(const float* __restrict__ sums, f32x2* __restrict__ table)
{
    int c = threadIdx.x;
    float m = sums[c * 2] * (1.f / NSP);
    float var = sums[c * 2 + 1] * (1.f / NSP) - m * m;
    table[c] = (f32x2){m, rsqrtf(var + EPS)};
}

// Fused: inorm2 apply (bf16 in) + skip add (fp32 x) + 2x2x2 maxpool.
__global__ __launch_bounds__(256) void inorm_skip_pool(
    const unsigned short* __restrict__ t2, const float* __restrict__ x,
    const float* __restrict__ sums,
    float* __restrict__ skip, float* __restrict__ down)
{
    int m = blockIdx.x * 256 + threadIdx.x;
    int c = m >> 12;
    int r = m & 4095;
    int oh = r >> 8, ow = (r >> 4) & 15, oz = r & 15;
    float mean = sums[c * 2] * (1.f / NSP);
    float inv = rsqrtf(sums[c * 2 + 1] * (1.f / NSP) - mean * mean + EPS);
    size_t base = (size_t)c * NSP + oh * 2048 + ow * 64 + oz * 2;
    float mx = -1e30f;
    #pragma unroll
    for (int dh = 0; dh < 2; ++dh)
    #pragma unroll
    for (int dw = 0; dw < 2; ++dw) {
        size_t a = base + dh * 1024 + dw * 32;
        us2 tv = *(const us2*)(t2 + a);
        f32x2 xv = *(const f32x2*)(x + a);
        f32x2 sv;
        sv.x = (bf2f(tv.x) - mean) * inv + xv.x;
        sv.y = (bf2f(tv.y) - mean) * inv + xv.y;
        *(f32x2*)(skip + a) = sv;
        mx = fmaxf(mx, fmaxf(sv.x, sv.y));
    }
    down[m] = mx;
}

// ---------------------------------------------------------------------------
extern "C" void kernel_launch(void* const* d_in, const int* in_sizes, int n_in,
                              void* d_out, int out_size, void* d_ws, size_t ws_size,
                              hipStream_t stream)
{
    const float* x      = (const float*)d_in[0];
    const float* qkv_w  = (const float*)d_in[1];
    const float* qkv_b  = (const float*)d_in[2];
    const float* proj_w = (const float*)d_in[3];
    const float* proj_b = (const float*)d_in[4];
    const float* rpb    = (const float*)d_in[5];
    const float* w1     = (const float*)d_in[6];
    const float* b1     = (const float*)d_in[7];
    const float* w2     = (const float*)d_in[8];
    const float* b2     = (const float*)d_in[9];

    float* out  = (float*)d_out;
    float* down = out;              // 2 MB, dead until final kernel
    float* skip = out + 524288;

    // Weight stash in the dead `down` region (384 KB < 2 MB)
    unsigned short* wb      = (unsigned short*)d_out;
    unsigned short* qkv_sw  = wb;
    unsigned short* proj_sw = wb + 49152;
    unsigned short* w1_sw   = wb + 65536;
    unsigned short* w2_sw   = wb + 131072;

    char* ws = (char*)d_ws;
    const size_t MB = 1u << 20;
    unsigned short* qkvT    = (unsigned short*)(ws);            //  0..24 MB
    unsigned short* samT    = (unsigned short*)(ws + 24 * MB);  // 24..32 MB [n][128]
    unsigned short* yb      = (unsigned short*)(ws + 32 * MB);  // 32..40 MB [c][n]
    unsigned short* hiddenT = (unsigned short*)(ws);            //  0..32 MB [n][512] (overlays qkvT+samT)
    unsigned short* t2b     = (unsigned short*)(ws + 48 * MB);  // 48..56 MB [c][n]
    float*          sums    = (float*)(ws + 72 * MB);           // 512 floats
    f32x2*          table1  = (f32x2*)(ws + 72 * MB + 4096);    // 128 pairs
    float* sums1 = sums;
    float* sums2 = sums + 256;

    // 0) all weight prep + zero sums (one kernel)
    prep_all<<<769, 256, 0, stream>>>(qkv_w, proj_w, w1, w2,
                                      qkv_sw, proj_sw, w1_sw, w2_sw, sums);

    // 1) qkv = x @ qkv_w^T + b -> transposed bf16 qkvT
    gemm_mfma<128, 0, 2><<<dim3(256, 3), 256, 0, stream>>>(
        qkv_sw, x, qkv_b, nullptr, nullptr, qkvT, 128, 0, 0);
    // 2) attention -> samT [n][128]
    attn_kernel<<<dim3(128, 8), 256, 0, stream>>>(qkvT, rpb, samT);
    // 3) proj (O=128, K=128): B from samT rows -> yb [c][n]
    gemm_mfma<64, 2, 1><<<dim3(512, 1), 256, 0, stream>>>(
        proj_sw, samT, proj_b, nullptr, nullptr, yb, 128, 0, 128);
    // 4) instance norm 1 stats
    inorm_partial_bf16<<<1024, 256, 0, stream>>>(yb, sums1);
    finalize_sums<<<1, 128, 0, stream>>>(sums1, table1);
    // 5a) hidden = relu(norm(yb) @ w1 + b1) -> hiddenT [n][512]
    gemm_mfma<128, 3, 3><<<dim3(256, 4), 256, 0, stream>>>(
        w1_sw, yb, b1, nullptr, table1, hiddenT, 128, 1, 512);
    // 5b) t2 = norm(yb) + hiddenT @ w2 + b2 -> t2b [c][n]
    gemm_mfma<64, 2, 1><<<dim3(512, 1), 256, 0, stream>>>(
        w2_sw, hiddenT, b2, yb, table1, t2b, 512, 0, 512);
    // 6) instance norm 2 stats
    inorm_partial_bf16<<<1024, 256, 0, stream>>>(t2b, sums2);
    // 7) fused inorm2 apply + skip + maxpool
    inorm_skip_pool<<<2048, 256, 0, stream>>>(t2b, x, sums2, skip, down);
}

// Round 10
// 158.884 us; speedup vs baseline: 3.2578x; 1.2022x over previous
//
#include <hip/hip_runtime.h>

#define NSP 32768   // 32*32*32 spatial positions
#define EPS 1e-5f

typedef __attribute__((ext_vector_type(8))) __bf16 bf16x8;
typedef __attribute__((ext_vector_type(4))) float f32x4;
typedef __attribute__((ext_vector_type(2))) float f32x2;
typedef __attribute__((ext_vector_type(8))) unsigned short us8;
typedef __attribute__((ext_vector_type(2))) unsigned short us2;

union U8 { us8 u; bf16x8 b; };

__device__ __forceinline__ unsigned short f2bf(float f) {
    unsigned u = __float_as_uint(f);
    u += 0x7fff + ((u >> 16) & 1);
    return (unsigned short)(u >> 16);
}
__device__ __forceinline__ float bf2f(unsigned short h) {
    return __uint_as_float(((unsigned)h) << 16);
}

// ---------------------------------------------------------------------------
// Weight prep (all 4 weights + zero sums in ONE kernel).
// bf16 pre-swizzled LDS tile images for 128(o) x 64(k) tiles.
// byte = r*128 + ((c*16) ^ ((r&7)<<4)) + 2j holds W[ob*128+r][ks*64+c*8+j].
// ---------------------------------------------------------------------------
__device__ __forceinline__ void prep_range(
    const float* __restrict__ W, int sO, int sC, int ntk,
    unsigned short* __restrict__ Wsw, int i)
{
    int tile = i >> 13;
    int s = i & 8191;
    int r = s >> 6;
    int byte = (s & 63) << 1;
    int ub = byte ^ ((r & 7) << 4);
    int c = ub >> 4;
    int j = (ub >> 1) & 7;
    int ob = tile / ntk;
    int ks = tile - ob * ntk;
    Wsw[i] = f2bf(W[(ob * 128 + r) * sO + (ks * 64 + c * 8 + j) * sC]);
}

__global__ __launch_bounds__(256) void prep_all(
    const float* __restrict__ qkv_w, const float* __restrict__ proj_w,
    const float* __restrict__ w1, const float* __restrict__ w2,
    unsigned short* __restrict__ qkv_sw, unsigned short* __restrict__ proj_sw,
    unsigned short* __restrict__ w1_sw, unsigned short* __restrict__ w2_sw,
    float* __restrict__ sums)
{
    int bid = blockIdx.x, tid = threadIdx.x;
    if (bid < 192)       prep_range(qkv_w, 128, 1, 2, qkv_sw, bid * 256 + tid);
    else if (bid < 256)  prep_range(proj_w, 128, 1, 2, proj_sw, (bid - 192) * 256 + tid);
    else if (bid < 512)  prep_range(w1, 1, 512, 2, w1_sw, (bid - 256) * 256 + tid);
    else if (bid < 768)  prep_range(w2, 1, 128, 8, w2_sw, (bid - 512) * 256 + tid);
    else { sums[tid] = 0.f; sums[tid + 256] = 0.f; }
}

// ---------------------------------------------------------------------------
// bf16 MFMA GEMM, register-prefetch pipelined.
// Block tile 128(o) x BN(n) x BK=64, 4 waves (2x2).
// XMODE: 0 = fp32 [k][NSP]; 2 = bf16 rows [n][RW] (vector chunk load)
// OMODE: 1 = bf16 [o][NSP]; 2 = qkvT layout (BN=128 only)
// ---------------------------------------------------------------------------
template<int BN, int XMODE, int OMODE>
__global__ __launch_bounds__(256) void gemm_mfma(
    const unsigned short* __restrict__ Wsw,
    const void* __restrict__ X,
    const float* __restrict__ bias,
    void* __restrict__ Out,
    int K, int rw)
{
    constexpr int NF = BN / 32;
    constexpr int BCH = BN / 32;
    __shared__ __align__(16) unsigned short smem[8192 + BN * 64];
    unsigned short* Asm = smem;
    unsigned short* Bsm = smem + 8192;
    const int tid  = threadIdx.x;
    const int lane = tid & 63;
    const int wid  = tid >> 6;
    const int wr   = wid >> 1, wc = wid & 1;
    const int n0   = blockIdx.x * BN;
    const int o0   = blockIdx.y << 7;
    const int nk   = K >> 6;

    f32x4 acc[4][NF];
    #pragma unroll
    for (int m = 0; m < 4; ++m)
        #pragma unroll
        for (int n = 0; n < NF; ++n)
            acc[m][n] = (f32x4){0.f, 0.f, 0.f, 0.f};

    const int r  = (BN == 128) ? (tid & 127) : (tid & 63);
    const int kh = (BN == 128) ? (tid >> 7)  : (tid >> 6);

    us8 a_pre[4];
    us8 b_pre[BCH];
    int b_c[BCH];
    #pragma unroll
    for (int i = 0; i < BCH; ++i)
        b_c[i] = (BN == 128) ? (((((r >> 5) + i) & 3) << 1) + kh)
                             : (((((r >> 4) + i) & 1) << 2) + kh);

    auto load_tile = [&](int ks) {
        const char* gbase = (const char*)(Wsw + (size_t)(blockIdx.y * nk + ks) * 8192);
        #pragma unroll
        for (int i = 0; i < 4; ++i)
            a_pre[i] = *(const us8*)(gbase + i * 4096 + tid * 16);
        #pragma unroll
        for (int i = 0; i < BCH; ++i) {
            int c = b_c[i];
            int kb = (ks << 6) + (c << 3);
            us8 bv;
            if (XMODE == 0) {
                const float* xp = (const float*)X + (size_t)kb * NSP + n0 + r;
                #pragma unroll
                for (int j = 0; j < 8; ++j) bv[j] = f2bf(xp[(size_t)j * NSP]);
            } else {
                bv = *(const us8*)((const unsigned short*)X + (size_t)(n0 + r) * rw + kb);
            }
            b_pre[i] = bv;
        }
    };
    auto store_tile = [&]() {
        #pragma unroll
        for (int i = 0; i < 4; ++i)
            *(us8*)((char*)Asm + i * 4096 + tid * 16) = a_pre[i];
        #pragma unroll
        for (int i = 0; i < BCH; ++i) {
            int off = (r << 7) + ((b_c[i] << 4) ^ ((r & 7) << 4));
            *(us8*)((char*)Bsm + off) = b_pre[i];
        }
    };

    load_tile(0);
    store_tile();
    __syncthreads();

    for (int ks = 0; ks < nk; ++ks) {
        if (ks + 1 < nk) load_tile(ks + 1);
        #pragma unroll
        for (int ki = 0; ki < 2; ++ki) {
            bf16x8 af[4], bfr[NF];
            int chunk = (ki << 2) + (lane >> 4);
            #pragma unroll
            for (int m = 0; m < 4; ++m) {
                int row = (wr << 6) + (m << 4) + (lane & 15);
                int off = (row << 7) + ((chunk << 4) ^ ((row & 7) << 4));
                U8 t; t.u = *(const us8*)((const char*)Asm + off);
                af[m] = t.b;
            }
            #pragma unroll
            for (int n = 0; n < NF; ++n) {
                int row = wc * (BN / 2) + (n << 4) + (lane & 15);
                int off = (row << 7) + ((chunk << 4) ^ ((row & 7) << 4));
                U8 t; t.u = *(const us8*)((const char*)Bsm + off);
                bfr[n] = t.b;
            }
            #pragma unroll
            for (int m = 0; m < 4; ++m)
                #pragma unroll
                for (int n = 0; n < NF; ++n)
                    acc[m][n] = __builtin_amdgcn_mfma_f32_16x16x32_bf16(af[m], bfr[n], acc[m][n], 0, 0, 0);
        }
        if (ks + 1 < nk) {
            __syncthreads();
            store_tile();
            __syncthreads();
        }
    }

    if (BN == 128 && OMODE == 2) {
        __syncthreads();
        unsigned short* Wt = smem + (wid << 12);
        #pragma unroll
        for (int m = 0; m < 4; ++m)
            #pragma unroll
            for (int reg = 0; reg < 4; ++reg) {
                int ol = (m << 4) + ((lane >> 4) << 2) + reg;
                float b = bias[o0 + (wr << 6) + ol];
                #pragma unroll
                for (int n = 0; n < NF; ++n) {
                    int cl = (n << 4) + (lane & 15);
                    Wt[ol * 64 + (cl ^ ((ol & 7) << 3))] = f2bf(acc[m][n][reg] + b);
                }
            }
        const int d = lane & 15, coff = lane >> 4;
        unsigned short* O = (unsigned short*)Out;
        #pragma unroll
        for (int go = 0; go < 4; ++go) {
            int g = (wr << 2) + go;
            #pragma unroll
            for (int cc = 0; cc < 16; ++cc) {
                int cl = (cc << 2) + coff;
                int ol = (go << 4) + d;
                unsigned short v = Wt[ol * 64 + (cl ^ ((ol & 7) << 3))];
                size_t idx = ((size_t)((blockIdx.y << 3) + g) * NSP + n0 + (wc << 6) + cl) * 16 + d;
                O[idx] = v;
            }
        }
        return;
    }

    // OMODE 1: bf16 [o][NSP]
    #pragma unroll
    for (int m = 0; m < 4; ++m) {
        #pragma unroll
        for (int reg = 0; reg < 4; ++reg) {
            int o = o0 + (wr << 6) + (m << 4) + ((lane >> 4) << 2) + reg;
            float b = bias[o];
            #pragma unroll
            for (int n = 0; n < NF; ++n) {
                int col = n0 + wc * (BN / 2) + (n << 4) + (lane & 15);
                size_t oi = (size_t)o * NSP + col;
                ((unsigned short*)Out)[oi] = f2bf(acc[m][n][reg] + b);
            }
        }
    }
}

// ---------------------------------------------------------------------------
// Fused MLP: t2 = norm(yb) + W2^T relu(W1^T norm(yb) + b1) + b2.
// Block = 64 n-cols, 4 waves (2x2: wr over o-halves, wc over n-halves).
// X (=norm(yb), 128k x 64n) staged once in LDS; hidden never leaves LDS.
// ---------------------------------------------------------------------------
__global__ __launch_bounds__(256) void mlp_kernel(
    const unsigned short* __restrict__ w1_sw,   // 8 tiles: chunk c -> tiles c*2, c*2+1
    const unsigned short* __restrict__ w2_sw,   // 8 tiles: chunk c -> tiles c*2, c*2+1
    const unsigned short* __restrict__ yb,      // bf16 [128][NSP]
    const float* __restrict__ sums1,            // per-ch (s, ss)
    const float* __restrict__ b1, const float* __restrict__ b2,
    unsigned short* __restrict__ t2b)           // bf16 [128][NSP]
{
    __shared__ __align__(16) unsigned short smem[32768];   // 64 KB
    unsigned short* Asm = smem;              // 32 KB: 2 k-tiles of current weight chunk
    unsigned short* Xs  = smem + 16384;      // 16 KB: X, 2 k-tiles (64 rows x 64 k each)
    unsigned short* Hs  = smem + 24576;      // 16 KB: H chunk, 2 k-tiles
    const int tid  = threadIdx.x;
    const int lane = tid & 63;
    const int wid  = tid >> 6;
    const int wr   = wid >> 1, wc = wid & 1;
    const int n0   = blockIdx.x << 6;

    // ---- stage X = norm(yb) into swizzled B-layout (table inline from sums1)
    {
        const int r = tid & 63, q = tid >> 6;
        #pragma unroll
        for (int i = 0; i < 4; ++i) {
            int ch = q + (i << 2);            // chunk 0..15 (8 k each)
            int k0 = ch << 3;
            us8 bv;
            #pragma unroll
            for (int j = 0; j < 8; ++j) {
                int k = k0 + j;
                float mmean = sums1[k * 2] * (1.f / NSP);
                float inv = rsqrtf(sums1[k * 2 + 1] * (1.f / NSP) - mmean * mmean + EPS);
                bv[j] = f2bf((bf2f(yb[(size_t)k * NSP + n0 + r]) - mmean) * inv);
            }
            int off = ((ch >> 3) << 13) + (r << 7) + (((ch & 7) << 4) ^ ((r & 7) << 4));
            *(us8*)((char*)Xs + off) = bv;
        }
    }
    __syncthreads();

    f32x4 acc2[4][2];
    #pragma unroll
    for (int m = 0; m < 4; ++m)
        #pragma unroll
        for (int n = 0; n < 2; ++n)
            acc2[m][n] = (f32x4){0.f, 0.f, 0.f, 0.f};

    for (int c = 0; c < 4; ++c) {
        if (c) __syncthreads();               // prior W2 reads of Asm/Hs done
        // stage W1 chunk c (2 tiles = 32 KB)
        {
            const char* g = (const char*)(w1_sw + (size_t)c * 16384);
            #pragma unroll
            for (int i = 0; i < 8; ++i)
                *(us8*)((char*)Asm + i * 4096 + tid * 16) = *(const us8*)(g + i * 4096 + tid * 16);
        }
        __syncthreads();
        // H-chunk = W1c^T X  (accumulate over full K=128)
        f32x4 accH[4][2];
        #pragma unroll
        for (int m = 0; m < 4; ++m)
            #pragma unroll
            for (int n = 0; n < 2; ++n)
                accH[m][n] = (f32x4){0.f, 0.f, 0.f, 0.f};
        #pragma unroll
        for (int kt = 0; kt < 2; ++kt) {
            #pragma unroll
            for (int ki = 0; ki < 2; ++ki) {
                int chunk = (ki << 2) + (lane >> 4);
                bf16x8 af[4], bfr[2];
                #pragma unroll
                for (int m = 0; m < 4; ++m) {
                    int row = (wr << 6) + (m << 4) + (lane & 15);
                    int off = (kt << 14) + (row << 7) + ((chunk << 4) ^ ((row & 7) << 4));
                    U8 t; t.u = *(const us8*)((const char*)Asm + off);
                    af[m] = t.b;
                }
                #pragma unroll
                for (int n = 0; n < 2; ++n) {
                    int row = (wc << 5) + (n << 4) + (lane & 15);
                    int off = (kt << 13) + (row << 7) + ((chunk << 4) ^ ((row & 7) << 4));
                    U8 t; t.u = *(const us8*)((const char*)Xs + off);
                    bfr[n] = t.b;
                }
                #pragma unroll
                for (int m = 0; m < 4; ++m)
                    #pragma unroll
                    for (int n = 0; n < 2; ++n)
                        accH[m][n] = __builtin_amdgcn_mfma_f32_16x16x32_bf16(af[m], bfr[n], accH[m][n], 0, 0, 0);
            }
        }
        // H = relu(accH + b1) -> Hs in B-layout (k2-rows = hidden channel)
        #pragma unroll
        for (int m = 0; m < 4; ++m)
            #pragma unroll
            for (int reg = 0; reg < 4; ++reg) {
                int ol = (m << 4) + ((lane >> 4) << 2) + reg;     // 0..63 within wr-half
                float bb = b1[(c << 7) + (wr << 6) + ol];
                #pragma unroll
                for (int n = 0; n < 2; ++n) {
                    int row = (wc << 5) + (n << 4) + (lane & 15); // n-local 0..63
                    float v = fmaxf(accH[m][n][reg] + bb, 0.f);
                    int byte = (wr << 13) + (row << 7) + (((ol >> 3) << 4) ^ ((row & 7) << 4)) + ((ol & 7) << 1);
                    *(unsigned short*)((char*)Hs + byte) = f2bf(v);
                }
            }
        __syncthreads();                       // H visible; Asm free (all MFMA_H done)
        // stage W2 chunk c
        {
            const char* g = (const char*)(w2_sw + (size_t)c * 16384);
            #pragma unroll
            for (int i = 0; i < 8; ++i)
                *(us8*)((char*)Asm + i * 4096 + tid * 16) = *(const us8*)(g + i * 4096 + tid * 16);
        }
        __syncthreads();
        // acc2 += W2c^T H
        #pragma unroll
        for (int kt = 0; kt < 2; ++kt) {
            #pragma unroll
            for (int ki = 0; ki < 2; ++ki) {
                int chunk = (ki << 2) + (lane >> 4);
                bf16x8 af[4], bfr[2];
                #pragma unroll
                for (int m = 0; m < 4; ++m) {
                    int row = (wr << 6) + (m << 4) + (lane & 15);
                    int off = (kt << 14) + (row << 7) + ((chunk << 4) ^ ((row & 7) << 4));
                    U8 t; t.u = *(const us8*)((const char*)Asm + off);
                    af[m] = t.b;
                }
                #pragma unroll
                for (int n = 0; n < 2; ++n) {
                    int row = (wc << 5) + (n << 4) + (lane & 15);
                    int off = (kt << 13) + (row << 7) + ((chunk << 4) ^ ((row & 7) << 4));
                    U8 t; t.u = *(const us8*)((const char*)Hs + off);
                    bfr[n] = t.b;
                }
                #pragma unroll
                for (int m = 0; m < 4; ++m)
                    #pragma unroll
                    for (int n = 0; n < 2; ++n)
                        acc2[m][n] = __builtin_amdgcn_mfma_f32_16x16x32_bf16(af[m], bfr[n], acc2[m][n], 0, 0, 0);
            }
        }
    }

    // ---- epilogue: t2 = acc2 + b2 + X(normed, from LDS)
    #pragma unroll
    for (int m = 0; m < 4; ++m)
        #pragma unroll
        for (int reg = 0; reg < 4; ++reg) {
            int o2 = (wr << 6) + (m << 4) + ((lane >> 4) << 2) + reg;
            float bb = b2[o2];
            #pragma unroll
            for (int n = 0; n < 2; ++n) {
                int nl = (wc << 5) + (n << 4) + (lane & 15);
                int xbyte = ((o2 >> 6) << 13) + (nl << 7)
                          + ((((o2 & 63) >> 3) << 4) ^ ((nl & 7) << 4)) + ((o2 & 7) << 1);
                float resid = bf2f(*(const unsigned short*)((const char*)Xs + xbyte));
                float v = acc2[m][n][reg] + bb + resid;
                t2b[(size_t)o2 * NSP + n0 + nl] = f2bf(v);
            }
        }
}

// ---------------------------------------------------------------------------
// Neighborhood attention on d-contiguous bf16 qkv. One thread per (g, pos).
// Output samT [n][128] bf16.
// ---------------------------------------------------------------------------
__global__ __launch_bounds__(256) void attn_kernel(
    const unsigned short* __restrict__ qkvT, const float* __restrict__ rpb,
    unsigned short* __restrict__ samT)
{
    const int g = blockIdx.y;
    const int n = blockIdx.x * 256 + threadIdx.x;
    const int h = n >> 10, w = (n >> 5) & 31, z = n & 31;
    const int ih0 = min(max(h - 1, 0), 29);
    const int iw0 = min(max(w - 1, 0), 29);
    const int iz0 = min(max(z - 1, 0), 29);

    const us8* qp = (const us8*)(qkvT + ((size_t)g * NSP + n) * 16);
    const unsigned short* kb = qkvT + (size_t)(8 + g) * NSP * 16;
    const unsigned short* vb = qkvT + (size_t)(16 + g) * NSP * 16;

    float q[16];
    {
        us8 q0 = qp[0], q1 = qp[1];
        #pragma unroll
        for (int j = 0; j < 8; ++j) { q[j] = bf2f(q0[j]); q[8 + j] = bf2f(q1[j]); }
    }

    float logits[27];
    int idx = 0;
    #pragma unroll
    for (int kh = 0; kh < 3; ++kh)
    #pragma unroll
    for (int kw = 0; kw < 3; ++kw)
    #pragma unroll
    for (int kz = 0; kz < 3; ++kz) {
        int hh = ih0 + kh, ww = iw0 + kw, zz = iz0 + kz;
        int nb = (hh << 10) + (ww << 5) + zz;
        const us8* kp = (const us8*)(kb + (size_t)nb * 16);
        us8 k0 = kp[0], k1 = kp[1];
        float s = 0.f;
        #pragma unroll
        for (int j = 0; j < 8; ++j) s += q[j] * bf2f(k0[j]);
        #pragma unroll
        for (int j = 0; j < 8; ++j) s += q[8 + j] * bf2f(k1[j]);
        int rh = hh - h + 2, rw = ww - w + 2, rz = zz - z + 2;
        logits[idx++] = s * 0.25f + rpb[g * 125 + rh * 25 + rw * 5 + rz];
    }

    float mx = -1e30f;
    #pragma unroll
    for (int i = 0; i < 27; ++i) mx = fmaxf(mx, logits[i]);
    float sum = 0.f;
    #pragma unroll
    for (int i = 0; i < 27; ++i) { logits[i] = __expf(logits[i] - mx); sum += logits[i]; }
    float inv = 1.f / sum;

    float o[16] = {};
    idx = 0;
    #pragma unroll
    for (int kh = 0; kh < 3; ++kh)
    #pragma unroll
    for (int kw = 0; kw < 3; ++kw)
    #pragma unroll
    for (int kz = 0; kz < 3; ++kz) {
        int nb = ((ih0 + kh) << 10) + ((iw0 + kw) << 5) + (iz0 + kz);
        const us8* vp = (const us8*)(vb + (size_t)nb * 16);
        us8 v0 = vp[0], v1 = vp[1];
        float a = logits[idx++] * inv;
        #pragma unroll
        for (int j = 0; j < 8; ++j) { o[j] += a * bf2f(v0[j]); o[8 + j] += a * bf2f(v1[j]); }
    }
    us8 o0v, o1v;
    #pragma unroll
    for (int j = 0; j < 8; ++j) { o0v[j] = f2bf(o[j]); o1v[j] = f2bf(o[8 + j]); }
    us8* op = (us8*)(samT + (size_t)n * 128 + g * 16);
    op[0] = o0v; op[1] = o1v;
}

// ---------------------------------------------------------------------------
// Instance norm partials from bf16 [c][n] input (8 blocks/channel)
// ---------------------------------------------------------------------------
__global__ __launch_bounds__(256) void inorm_partial_bf16(
    const unsigned short* __restrict__ in, float* __restrict__ sums)
{
    const int c = blockIdx.x >> 3, seg = blockIdx.x & 7;
    const us8* p = (const us8*)(in + (size_t)c * NSP + seg * 4096);
    float s = 0.f, ss = 0.f;
    #pragma unroll
    for (int i = 0; i < 2; ++i) {
        us8 v = p[threadIdx.x + i * 256];
        #pragma unroll
        for (int j = 0; j < 8; ++j) { float f = bf2f(v[j]); s += f; ss += f * f; }
    }
    for (int off = 32; off > 0; off >>= 1) {
        s  += __shfl_down(s, off);
        ss += __shfl_down(ss, off);
    }
    __shared__ float red[2][4];
    int wid = threadIdx.x >> 6;
    if ((threadIdx.x & 63) == 0) { red[0][wid] = s; red[1][wid] = ss; }
    __syncthreads();
    if (threadIdx.x == 0) {
        atomicAdd(&sums[c * 2],     red[0][0] + red[0][1] + red[0][2] + red[0][3]);
        atomicAdd(&sums[c * 2 + 1], red[1][0] + red[1][1] + red[1][2] + red[1][3]);
    }
}

// Fused: inorm2 apply (bf16 in) + skip add (fp32 x) + 2x2x2 maxpool.
__global__ __launch_bounds__(256) void inorm_skip_pool(
    const unsigned short* __restrict__ t2, const float* __restrict__ x,
    const float* __restrict__ sums,
    float* __restrict__ skip, float* __restrict__ down)
{
    int m = blockIdx.x * 256 + threadIdx.x;
    int c = m >> 12;
    int r = m & 4095;
    int oh = r >> 8, ow = (r >> 4) & 15, oz = r & 15;
    float mean = sums[c * 2] * (1.f / NSP);
    float inv = rsqrtf(sums[c * 2 + 1] * (1.f / NSP) - mean * mean + EPS);
    size_t base = (size_t)c * NSP + oh * 2048 + ow * 64 + oz * 2;
    float mx = -1e30f;
    #pragma unroll
    for (int dh = 0; dh < 2; ++dh)
    #pragma unroll
    for (int dw = 0; dw < 2; ++dw) {
        size_t a = base + dh * 1024 + dw * 32;
        us2 tv = *(const us2*)(t2 + a);
        f32x2 xv = *(const f32x2*)(x + a);
        f32x2 sv;
        sv.x = (bf2f(tv.x) - mean) * inv + xv.x;
        sv.y = (bf2f(tv.y) - mean) * inv + xv.y;
        *(f32x2*)(skip + a) = sv;
        mx = fmaxf(mx, fmaxf(sv.x, sv.y));
    }
    down[m] = mx;
}

// ---------------------------------------------------------------------------
extern "C" void kernel_launch(void* const* d_in, const int* in_sizes, int n_in,
                              void* d_out, int out_size, void* d_ws, size_t ws_size,
                              hipStream_t stream)
{
    const float* x      = (const float*)d_in[0];
    const float* qkv_w  = (const float*)d_in[1];
    const float* qkv_b  = (const float*)d_in[2];
    const float* proj_w = (const float*)d_in[3];
    const float* proj_b = (const float*)d_in[4];
    const float* rpb    = (const float*)d_in[5];
    const float* w1     = (const float*)d_in[6];
    const float* b1     = (const float*)d_in[7];
    const float* w2     = (const float*)d_in[8];
    const float* b2     = (const float*)d_in[9];

    float* out  = (float*)d_out;
    float* down = out;              // 2 MB, dead until final kernel
    float* skip = out + 524288;

    // Weight stash in the dead `down` region (384 KB < 2 MB)
    unsigned short* wb      = (unsigned short*)d_out;
    unsigned short* qkv_sw  = wb;
    unsigned short* proj_sw = wb + 49152;
    unsigned short* w1_sw   = wb + 65536;
    unsigned short* w2_sw   = wb + 131072;

    char* ws = (char*)d_ws;
    const size_t MB = 1u << 20;
    unsigned short* qkvT    = (unsigned short*)(ws);            //  0..24 MB
    unsigned short* samT    = (unsigned short*)(ws + 24 * MB);  // 24..32 MB [n][128]
    unsigned short* yb      = (unsigned short*)(ws + 32 * MB);  // 32..40 MB [c][n]
    unsigned short* t2b     = (unsigned short*)(ws + 48 * MB);  // 48..56 MB [c][n]
    float*          sums    = (float*)(ws + 72 * MB);           // 512 floats
    float* sums1 = sums;
    float* sums2 = sums + 256;

    // 0) all weight prep + zero sums (one kernel)
    prep_all<<<769, 256, 0, stream>>>(qkv_w, proj_w, w1, w2,
                                      qkv_sw, proj_sw, w1_sw, w2_sw, sums);

    // 1) qkv = x @ qkv_w^T + b -> transposed bf16 qkvT
    gemm_mfma<128, 0, 2><<<dim3(256, 3), 256, 0, stream>>>(
        qkv_sw, x, qkv_b, qkvT, 128, 0);
    // 2) attention -> samT [n][128]
    attn_kernel<<<dim3(128, 8), 256, 0, stream>>>(qkvT, rpb, samT);
    // 3) proj (O=128, K=128): B from samT rows -> yb [c][n]
    gemm_mfma<64, 2, 1><<<dim3(512, 1), 256, 0, stream>>>(
        proj_sw, samT, proj_b, yb, 128, 128);
    // 4) instance norm 1 stats
    inorm_partial_bf16<<<1024, 256, 0, stream>>>(yb, sums1);
    // 5) fused MLP: t2 = norm(yb) + W2^T relu(W1^T norm(yb) + b1) + b2
    mlp_kernel<<<512, 256, 0, stream>>>(w1_sw, w2_sw, yb, sums1, b1, b2, t2b);
    // 6) instance norm 2 stats
    inorm_partial_bf16<<<1024, 256, 0, stream>>>(t2b, sums2);
    // 7) fused inorm2 apply + skip + maxpool
    inorm_skip_pool<<<2048, 256, 0, stream>>>(t2b, x, sums2, skip, down);
}